// Round 1
// baseline (4711.686 us; speedup 1.0000x reference)
//
#include <hip/hip_runtime.h>
#include <math.h>

#define N_NODES 100000
#define N_EDGES 1600000
#define IN_F 128
#define HID_F 128
#define OUT_F 64

// ---------------------------------------------------------------------------
// Fold KAN weights: Wf[b][k][o] ; plane0 = w + 0.1*c0, plane1 = 0.1*c1,
// plane2 = 0.1*c2.  Turns the KAN layer into a single GEMM with K = 3*IN_F.
// ---------------------------------------------------------------------------
__global__ __launch_bounds__(256) void fold_weights(
    const float* __restrict__ w1, const float* __restrict__ c1,
    const float* __restrict__ w2, const float* __restrict__ c2,
    float* __restrict__ Wf1, float* __restrict__ Wf2)
{
    int idx = blockIdx.x * 256 + threadIdx.x;
    if (idx < IN_F * HID_F) {
        Wf1[idx]                    = w1[idx] + 0.1f * c1[idx * 3 + 0];
        Wf1[idx + IN_F * HID_F]     = 0.1f * c1[idx * 3 + 1];
        Wf1[idx + 2 * IN_F * HID_F] = 0.1f * c1[idx * 3 + 2];
    }
    if (idx < IN_F * OUT_F) {
        Wf2[idx]                    = w2[idx] + 0.1f * c2[idx * 3 + 0];
        Wf2[idx + IN_F * OUT_F]     = 0.1f * c2[idx * 3 + 1];
        Wf2[idx + 2 * IN_F * OUT_F] = 0.1f * c2[idx * 3 + 2];
    }
}

// ---------------------------------------------------------------------------
// Degree: count incoming edges per node (atomic f32), then invert in place.
// ---------------------------------------------------------------------------
__global__ __launch_bounds__(256) void deg_count(
    const int* __restrict__ tgt, float* __restrict__ deg, int n_edges)
{
    int e = blockIdx.x * 256 + threadIdx.x;
    if (e < n_edges) atomicAdd(&deg[tgt[e]], 1.0f);
}

__global__ __launch_bounds__(256) void make_dinv(float* __restrict__ d, int n)
{
    int i = blockIdx.x * 256 + threadIdx.x;
    if (i < n) d[i] = 1.0f / fmaxf(d[i], 1.0f);
}

// ---------------------------------------------------------------------------
// KAN1 + ReLU.  One wave handles 8 nodes x 128 outputs (lane -> o, o+64).
// x addresses are wave-uniform -> scalar loads; weight reads coalesced+L1-hot.
// 100000 % 32 == 0 so no tail handling.
// ---------------------------------------------------------------------------
__global__ __launch_bounds__(256) void kan1_kernel(
    const float* __restrict__ x, const float* __restrict__ Wf,
    const float* __restrict__ bias, float* __restrict__ h1)
{
    const int lane  = threadIdx.x & 63;
    const int wave  = threadIdx.x >> 6;
    const int node0 = (blockIdx.x * 4 + wave) * 8;

    const float* W1 = Wf;
    const float* W2 = Wf + IN_F * HID_F;
    const float* W3 = Wf + 2 * IN_F * HID_F;

    float accA[8], accB[8];
#pragma unroll
    for (int j = 0; j < 8; ++j) { accA[j] = 0.f; accB[j] = 0.f; }

    for (int k = 0; k < IN_F; ++k) {
        float w1a = W1[k * HID_F + lane];
        float w1b = W1[k * HID_F + lane + 64];
        float w2a = W2[k * HID_F + lane];
        float w2b = W2[k * HID_F + lane + 64];
        float w3a = W3[k * HID_F + lane];
        float w3b = W3[k * HID_F + lane + 64];
#pragma unroll
        for (int j = 0; j < 8; ++j) {
            float xv = x[(node0 + j) * IN_F + k];
            float x2 = xv * xv;
            float x3 = x2 * xv;
            accA[j] = fmaf(xv, w1a, fmaf(x2, w2a, fmaf(x3, w3a, accA[j])));
            accB[j] = fmaf(xv, w1b, fmaf(x2, w2b, fmaf(x3, w3b, accB[j])));
        }
    }

    float ba = bias[lane], bb = bias[lane + 64];
#pragma unroll
    for (int j = 0; j < 8; ++j) {
        h1[(node0 + j) * HID_F + lane]      = fmaxf(accA[j] + ba, 0.f);
        h1[(node0 + j) * HID_F + lane + 64] = fmaxf(accB[j] + bb, 0.f);
    }
}

// ---------------------------------------------------------------------------
// KAN2.  Input row is the un-normalized aggregate; per-node 1/deg is fused
// into the load (must happen before the polynomial basis).  No ReLU.
// ---------------------------------------------------------------------------
__global__ __launch_bounds__(256) void kan2_kernel(
    const float* __restrict__ a1, const float* __restrict__ dinv,
    const float* __restrict__ Wf, const float* __restrict__ bias,
    float* __restrict__ h2)
{
    const int lane  = threadIdx.x & 63;
    const int wave  = threadIdx.x >> 6;
    const int node0 = (blockIdx.x * 4 + wave) * 8;

    const float* W1 = Wf;
    const float* W2 = Wf + IN_F * OUT_F;
    const float* W3 = Wf + 2 * IN_F * OUT_F;

    float acc[8], di[8];
#pragma unroll
    for (int j = 0; j < 8; ++j) { acc[j] = 0.f; di[j] = dinv[node0 + j]; }

    for (int k = 0; k < IN_F; ++k) {
        float w1 = W1[k * OUT_F + lane];
        float w2 = W2[k * OUT_F + lane];
        float w3 = W3[k * OUT_F + lane];
#pragma unroll
        for (int j = 0; j < 8; ++j) {
            float xv = a1[(node0 + j) * IN_F + k] * di[j];
            float x2 = xv * xv;
            float x3 = x2 * xv;
            acc[j] = fmaf(xv, w1, fmaf(x2, w2, fmaf(x3, w3, acc[j])));
        }
    }

    float b = bias[lane];
#pragma unroll
    for (int j = 0; j < 8; ++j)
        h2[(node0 + j) * OUT_F + lane] = acc[j] + b;
}

// ---------------------------------------------------------------------------
// Edge scatter (sum of h[source] into out[target]) via f32 atomics.
// 128-feature variant: 32 threads/edge, float4 per thread.
// ---------------------------------------------------------------------------
__global__ __launch_bounds__(256) void scatter128(
    const float* __restrict__ h, const int* __restrict__ src,
    const int* __restrict__ tgt, float* __restrict__ out, int n_edges)
{
    unsigned gid = blockIdx.x * 256u + threadIdx.x;
    int e = gid >> 5;
    if (e >= n_edges) return;
    int f = (gid & 31) << 2;
    int s = src[e], t = tgt[e];
    const float4 v = *(const float4*)(h + s * HID_F + f);
    float* o = out + t * HID_F + f;
    atomicAdd(o + 0, v.x);
    atomicAdd(o + 1, v.y);
    atomicAdd(o + 2, v.z);
    atomicAdd(o + 3, v.w);
}

// 64-feature variant: 16 threads/edge.
__global__ __launch_bounds__(256) void scatter64(
    const float* __restrict__ h, const int* __restrict__ src,
    const int* __restrict__ tgt, float* __restrict__ out, int n_edges)
{
    unsigned gid = blockIdx.x * 256u + threadIdx.x;
    int e = gid >> 4;
    if (e >= n_edges) return;
    int f = (gid & 15) << 2;
    int s = src[e], t = tgt[e];
    const float4 v = *(const float4*)(h + s * OUT_F + f);
    float* o = out + t * OUT_F + f;
    atomicAdd(o + 0, v.x);
    atomicAdd(o + 1, v.y);
    atomicAdd(o + 2, v.z);
    atomicAdd(o + 3, v.w);
}

// ---------------------------------------------------------------------------
// log_softmax over 64 features: one wave per node, lane = feature.
// Applies 1/deg of the second aggregation before the softmax.
// ---------------------------------------------------------------------------
__global__ __launch_bounds__(256) void logsoftmax_kernel(
    const float* __restrict__ a2, const float* __restrict__ dinv,
    float* __restrict__ out)
{
    const int lane = threadIdx.x & 63;
    const int wave = threadIdx.x >> 6;
    const int node = blockIdx.x * 4 + wave;
    if (node >= N_NODES) return;

    float v = a2[node * OUT_F + lane] * dinv[node];
    float m = v;
#pragma unroll
    for (int off = 32; off >= 1; off >>= 1)
        m = fmaxf(m, __shfl_xor(m, off));
    float e = expf(v - m);
    float s = e;
#pragma unroll
    for (int off = 32; off >= 1; off >>= 1)
        s += __shfl_xor(s, off);
    out[node * OUT_F + lane] = v - m - logf(s);
}

// ---------------------------------------------------------------------------
extern "C" void kernel_launch(void* const* d_in, const int* in_sizes, int n_in,
                              void* d_out, int out_size, void* d_ws, size_t ws_size,
                              hipStream_t stream)
{
    const float* x  = (const float*)d_in[0];
    const int*   ei = (const int*)d_in[1];
    const float* w1 = (const float*)d_in[2];
    const float* b1 = (const float*)d_in[3];
    const float* c1 = (const float*)d_in[4];
    const float* w2 = (const float*)d_in[5];
    const float* b2 = (const float*)d_in[6];
    const float* c2 = (const float*)d_in[7];
    float* out = (float*)d_out;

    const int* src = ei;            // edge_index[0]
    const int* tgt = ei + N_EDGES;  // edge_index[1]

    // workspace carve-up (256B aligned); bufA/bufB are reused across stages.
    char* ws = (char*)d_ws;
    size_t off = 0;
    auto carve = [&](size_t bytes) -> void* {
        void* p = ws + off;
        off = (off + bytes + 255) & ~(size_t)255;
        return p;
    };
    float* Wf1  = (float*)carve(3 * IN_F * HID_F * 4);
    float* Wf2  = (float*)carve(3 * IN_F * OUT_F * 4);
    float* dinv = (float*)carve((size_t)N_NODES * 4);
    float* bufA = (float*)carve((size_t)N_NODES * HID_F * 4);  // h1, then h2
    float* bufB = (float*)carve((size_t)N_NODES * HID_F * 4);  // a1, then a2

    hipMemsetAsync(dinv, 0, (size_t)N_NODES * 4, stream);
    fold_weights<<<64, 256, 0, stream>>>(w1, c1, w2, c2, Wf1, Wf2);
    deg_count<<<(N_EDGES + 255) / 256, 256, 0, stream>>>(tgt, dinv, N_EDGES);
    make_dinv<<<(N_NODES + 255) / 256, 256, 0, stream>>>(dinv, N_NODES);

    kan1_kernel<<<N_NODES / 32, 256, 0, stream>>>(x, Wf1, b1, bufA);

    hipMemsetAsync(bufB, 0, (size_t)N_NODES * HID_F * 4, stream);
    scatter128<<<(N_EDGES * 32 + 255) / 256, 256, 0, stream>>>(bufA, src, tgt, bufB, N_EDGES);

    kan2_kernel<<<N_NODES / 32, 256, 0, stream>>>(bufB, dinv, Wf2, b2, bufA);

    hipMemsetAsync(bufB, 0, (size_t)N_NODES * OUT_F * 4, stream);
    scatter64<<<(N_EDGES * 16 + 255) / 256, 256, 0, stream>>>(bufA, src, tgt, bufB, N_EDGES);

    logsoftmax_kernel<<<(N_NODES + 3) / 4, 256, 0, stream>>>(bufB, dinv, out);
}

// Round 2
// 921.499 us; speedup vs baseline: 5.1131x; 5.1131x over previous
//
#include <hip/hip_runtime.h>
#include <math.h>

#define N_NODES 100000
#define N_EDGES 1600000
#define IN_F 128
#define HID_F 128
#define OUT_F 64
#define NB_SCAN ((N_NODES + 255) / 256)   // 391 blocks in the 2-level scan

// ---------------------------------------------------------------------------
// Fold KAN weights: plane0 = w + 0.1*c0, plane1 = 0.1*c1, plane2 = 0.1*c2.
// ---------------------------------------------------------------------------
__global__ __launch_bounds__(256) void fold_weights(
    const float* __restrict__ w1, const float* __restrict__ c1,
    const float* __restrict__ w2, const float* __restrict__ c2,
    float* __restrict__ Wf1, float* __restrict__ Wf2)
{
    int idx = blockIdx.x * 256 + threadIdx.x;
    if (idx < IN_F * HID_F) {
        Wf1[idx]                    = w1[idx] + 0.1f * c1[idx * 3 + 0];
        Wf1[idx + IN_F * HID_F]     = 0.1f * c1[idx * 3 + 1];
        Wf1[idx + 2 * IN_F * HID_F] = 0.1f * c1[idx * 3 + 2];
    }
    if (idx < IN_F * OUT_F) {
        Wf2[idx]                    = w2[idx] + 0.1f * c2[idx * 3 + 0];
        Wf2[idx + IN_F * OUT_F]     = 0.1f * c2[idx * 3 + 1];
        Wf2[idx + 2 * IN_F * OUT_F] = 0.1f * c2[idx * 3 + 2];
    }
}

// ---------------------------------------------------------------------------
// CSR build: degree count -> 2-level exclusive scan -> slot fill.
// ---------------------------------------------------------------------------
__global__ __launch_bounds__(256) void deg_count(
    const int* __restrict__ tgt, int* __restrict__ deg, int n_edges)
{
    int e = blockIdx.x * 256 + threadIdx.x;
    if (e < n_edges) atomicAdd(&deg[tgt[e]], 1);
}

// level-1: per-256-chunk sums
__global__ __launch_bounds__(256) void scan_bsum(
    const int* __restrict__ deg, int* __restrict__ bsum, int n)
{
    __shared__ int s[256];
    int tid = threadIdx.x;
    int i = blockIdx.x * 256 + tid;
    s[tid] = (i < n) ? deg[i] : 0;
    __syncthreads();
    for (int o = 128; o > 0; o >>= 1) {
        if (tid < o) s[tid] += s[tid + o];
        __syncthreads();
    }
    if (tid == 0) bsum[blockIdx.x] = s[0];
}

// level-2: single-block exclusive scan of the 391 block sums
__global__ __launch_bounds__(512) void scan_top(int* __restrict__ bsum, int nb)
{
    __shared__ int s[512];
    int tid = threadIdx.x;
    int v = (tid < nb) ? bsum[tid] : 0;
    s[tid] = v;
    __syncthreads();
    for (int o = 1; o < 512; o <<= 1) {
        int t = (tid >= o) ? s[tid - o] : 0;
        __syncthreads();
        s[tid] += t;
        __syncthreads();
    }
    if (tid < nb) bsum[tid] = s[tid] - v;   // exclusive
}

// level-3: per-chunk exclusive scan + block offset; also seeds the fill cursor
__global__ __launch_bounds__(256) void scan_final(
    const int* __restrict__ deg, const int* __restrict__ bsum,
    int* __restrict__ row_start, int* __restrict__ cursor, int n)
{
    __shared__ int s[256];
    int tid = threadIdx.x;
    int i = blockIdx.x * 256 + tid;
    int v = (i < n) ? deg[i] : 0;
    s[tid] = v;
    __syncthreads();
    for (int o = 1; o < 256; o <<= 1) {
        int t = (tid >= o) ? s[tid - o] : 0;
        __syncthreads();
        s[tid] += t;
        __syncthreads();
    }
    int excl = s[tid] - v + bsum[blockIdx.x];
    if (i < n) { row_start[i] = excl; cursor[i] = excl; }
    if (i == n - 1) row_start[n] = excl + v;
}

__global__ __launch_bounds__(256) void csr_fill(
    const int* __restrict__ src, const int* __restrict__ tgt,
    int* __restrict__ cursor, int* __restrict__ csr_src, int n_edges)
{
    int e = blockIdx.x * 256 + threadIdx.x;
    if (e < n_edges) {
        int pos = atomicAdd(&cursor[tgt[e]], 1);
        csr_src[pos] = src[e];
    }
}

// ---------------------------------------------------------------------------
// KAN1 + ReLU.  One wave handles 8 nodes x 128 outputs (lane -> o, o+64).
// ---------------------------------------------------------------------------
__global__ __launch_bounds__(256) void kan1_kernel(
    const float* __restrict__ x, const float* __restrict__ Wf,
    const float* __restrict__ bias, float* __restrict__ h1)
{
    const int lane  = threadIdx.x & 63;
    const int wave  = threadIdx.x >> 6;
    const int node0 = (blockIdx.x * 4 + wave) * 8;

    const float* W1 = Wf;
    const float* W2 = Wf + IN_F * HID_F;
    const float* W3 = Wf + 2 * IN_F * HID_F;

    float accA[8], accB[8];
#pragma unroll
    for (int j = 0; j < 8; ++j) { accA[j] = 0.f; accB[j] = 0.f; }

    for (int k = 0; k < IN_F; ++k) {
        float w1a = W1[k * HID_F + lane];
        float w1b = W1[k * HID_F + lane + 64];
        float w2a = W2[k * HID_F + lane];
        float w2b = W2[k * HID_F + lane + 64];
        float w3a = W3[k * HID_F + lane];
        float w3b = W3[k * HID_F + lane + 64];
#pragma unroll
        for (int j = 0; j < 8; ++j) {
            float xv = x[(node0 + j) * IN_F + k];
            float x2 = xv * xv;
            float x3 = x2 * xv;
            accA[j] = fmaf(xv, w1a, fmaf(x2, w2a, fmaf(x3, w3a, accA[j])));
            accB[j] = fmaf(xv, w1b, fmaf(x2, w2b, fmaf(x3, w3b, accB[j])));
        }
    }

    float ba = bias[lane], bb = bias[lane + 64];
#pragma unroll
    for (int j = 0; j < 8; ++j) {
        h1[(node0 + j) * HID_F + lane]      = fmaxf(accA[j] + ba, 0.f);
        h1[(node0 + j) * HID_F + lane + 64] = fmaxf(accB[j] + bb, 0.f);
    }
}

// ---------------------------------------------------------------------------
// Gather-aggregate over 128 feats: one wave per node, lane holds float2.
// CSR edge list broadcast via shuffle (one coalesced batch load per 64 edges).
// ---------------------------------------------------------------------------
__global__ __launch_bounds__(256) void gather128(
    const float* __restrict__ h, const int* __restrict__ row_start,
    const int* __restrict__ csr_src, float* __restrict__ out)
{
    const int lane = threadIdx.x & 63;
    const int wave = threadIdx.x >> 6;
    const int node = blockIdx.x * 4 + wave;
    if (node >= N_NODES) return;

    int e0 = row_start[node], e1 = row_start[node + 1];
    const float2* hp = (const float2*)h;
    float ax = 0.f, ay = 0.f;

    for (int base = e0; base < e1; base += 64) {
        int idx = base + lane;
        int sreg = (idx < e1) ? csr_src[idx] : 0;
        int cnt = min(64, e1 - base);
        for (int j = 0; j < cnt; ++j) {
            int sj = __shfl(sreg, j);
            float2 v = hp[sj * 64 + lane];
            ax += v.x; ay += v.y;
        }
    }
    float2 r; r.x = ax; r.y = ay;
    ((float2*)out)[node * 64 + lane] = r;
}

// ---------------------------------------------------------------------------
// KAN2: input row = un-normalized aggregate; 1/deg fused into the load.
// ---------------------------------------------------------------------------
__global__ __launch_bounds__(256) void kan2_kernel(
    const float* __restrict__ a1, const int* __restrict__ deg,
    const float* __restrict__ Wf, const float* __restrict__ bias,
    float* __restrict__ h2)
{
    const int lane  = threadIdx.x & 63;
    const int wave  = threadIdx.x >> 6;
    const int node0 = (blockIdx.x * 4 + wave) * 8;

    const float* W1 = Wf;
    const float* W2 = Wf + IN_F * OUT_F;
    const float* W3 = Wf + 2 * IN_F * OUT_F;

    float acc[8], di[8];
#pragma unroll
    for (int j = 0; j < 8; ++j) {
        acc[j] = 0.f;
        di[j] = 1.0f / fmaxf((float)deg[node0 + j], 1.0f);
    }

    for (int k = 0; k < IN_F; ++k) {
        float w1 = W1[k * OUT_F + lane];
        float w2 = W2[k * OUT_F + lane];
        float w3 = W3[k * OUT_F + lane];
#pragma unroll
        for (int j = 0; j < 8; ++j) {
            float xv = a1[(node0 + j) * IN_F + k] * di[j];
            float x2 = xv * xv;
            float x3 = x2 * xv;
            acc[j] = fmaf(xv, w1, fmaf(x2, w2, fmaf(x3, w3, acc[j])));
        }
    }

    float b = bias[lane];
#pragma unroll
    for (int j = 0; j < 8; ++j)
        h2[(node0 + j) * OUT_F + lane] = acc[j] + b;
}

// ---------------------------------------------------------------------------
// Gather-aggregate over 64 feats fused with 1/deg + log_softmax.
// One wave per node, lane = feature.
// ---------------------------------------------------------------------------
__global__ __launch_bounds__(256) void gather64_lsm(
    const float* __restrict__ h, const int* __restrict__ row_start,
    const int* __restrict__ csr_src, const int* __restrict__ deg,
    float* __restrict__ out)
{
    const int lane = threadIdx.x & 63;
    const int wave = threadIdx.x >> 6;
    const int node = blockIdx.x * 4 + wave;
    if (node >= N_NODES) return;

    int e0 = row_start[node], e1 = row_start[node + 1];
    float acc = 0.f;

    for (int base = e0; base < e1; base += 64) {
        int idx = base + lane;
        int sreg = (idx < e1) ? csr_src[idx] : 0;
        int cnt = min(64, e1 - base);
        for (int j = 0; j < cnt; ++j) {
            int sj = __shfl(sreg, j);
            acc += h[sj * OUT_F + lane];
        }
    }

    float di = 1.0f / fmaxf((float)deg[node], 1.0f);
    float v = acc * di;

    float m = v;
#pragma unroll
    for (int off = 32; off >= 1; off >>= 1)
        m = fmaxf(m, __shfl_xor(m, off));
    float e = expf(v - m);
    float s = e;
#pragma unroll
    for (int off = 32; off >= 1; off >>= 1)
        s += __shfl_xor(s, off);
    out[node * OUT_F + lane] = v - m - logf(s);
}

// ---------------------------------------------------------------------------
extern "C" void kernel_launch(void* const* d_in, const int* in_sizes, int n_in,
                              void* d_out, int out_size, void* d_ws, size_t ws_size,
                              hipStream_t stream)
{
    const float* x  = (const float*)d_in[0];
    const int*   ei = (const int*)d_in[1];
    const float* w1 = (const float*)d_in[2];
    const float* b1 = (const float*)d_in[3];
    const float* c1 = (const float*)d_in[4];
    const float* w2 = (const float*)d_in[5];
    const float* b2 = (const float*)d_in[6];
    const float* c2 = (const float*)d_in[7];
    float* out = (float*)d_out;

    const int* src = ei;            // edge_index[0]
    const int* tgt = ei + N_EDGES;  // edge_index[1]

    char* ws = (char*)d_ws;
    size_t off = 0;
    auto carve = [&](size_t bytes) -> void* {
        void* p = ws + off;
        off = (off + bytes + 255) & ~(size_t)255;
        return p;
    };
    float* Wf1      = (float*)carve(3 * IN_F * HID_F * 4);
    float* Wf2      = (float*)carve(3 * IN_F * OUT_F * 4);
    int*   deg      = (int*)carve((size_t)N_NODES * 4);
    int*   row_start= (int*)carve(((size_t)N_NODES + 1) * 4);
    int*   cursor   = (int*)carve((size_t)N_NODES * 4);
    int*   bsum     = (int*)carve((size_t)NB_SCAN * 4);
    int*   csr_src  = (int*)carve((size_t)N_EDGES * 4);
    float* bufA     = (float*)carve((size_t)N_NODES * HID_F * 4);  // h1, then h2
    float* bufB     = (float*)carve((size_t)N_NODES * HID_F * 4);  // a1

    // --- CSR build -----------------------------------------------------------
    hipMemsetAsync(deg, 0, (size_t)N_NODES * 4, stream);
    deg_count<<<(N_EDGES + 255) / 256, 256, 0, stream>>>(tgt, deg, N_EDGES);
    scan_bsum<<<NB_SCAN, 256, 0, stream>>>(deg, bsum, N_NODES);
    scan_top<<<1, 512, 0, stream>>>(bsum, NB_SCAN);
    scan_final<<<NB_SCAN, 256, 0, stream>>>(deg, bsum, row_start, cursor, N_NODES);
    csr_fill<<<(N_EDGES + 255) / 256, 256, 0, stream>>>(src, tgt, cursor, csr_src, N_EDGES);

    // --- weights + layer 1 ---------------------------------------------------
    fold_weights<<<64, 256, 0, stream>>>(w1, c1, w2, c2, Wf1, Wf2);
    kan1_kernel<<<N_NODES / 32, 256, 0, stream>>>(x, Wf1, b1, bufA);

    // --- aggregate 1 (gather, no atomics) ------------------------------------
    gather128<<<(N_NODES + 3) / 4, 256, 0, stream>>>(bufA, row_start, csr_src, bufB);

    // --- layer 2 -------------------------------------------------------------
    kan2_kernel<<<N_NODES / 32, 256, 0, stream>>>(bufB, deg, Wf2, b2, bufA);

    // --- aggregate 2 + log_softmax (fused) -----------------------------------
    gather64_lsm<<<(N_NODES + 3) / 4, 256, 0, stream>>>(bufA, row_start, csr_src, deg, out);
}

// Round 3
// 781.351 us; speedup vs baseline: 6.0302x; 1.1794x over previous
//
#include <hip/hip_runtime.h>
#include <math.h>

#define N_NODES 100000
#define N_EDGES 1600000
#define IN_F 128
#define HID_F 128
#define OUT_F 64
#define NB_SCAN ((N_NODES + 255) / 256)   // 391 blocks in the 2-level scan

// ---------------------------------------------------------------------------
// Fold KAN weights: plane0 = w + 0.1*c0, plane1 = 0.1*c1, plane2 = 0.1*c2.
// ---------------------------------------------------------------------------
__global__ __launch_bounds__(256) void fold_weights(
    const float* __restrict__ w1, const float* __restrict__ c1,
    const float* __restrict__ w2, const float* __restrict__ c2,
    float* __restrict__ Wf1, float* __restrict__ Wf2)
{
    int idx = blockIdx.x * 256 + threadIdx.x;
    if (idx < IN_F * HID_F) {
        Wf1[idx]                    = w1[idx] + 0.1f * c1[idx * 3 + 0];
        Wf1[idx + IN_F * HID_F]     = 0.1f * c1[idx * 3 + 1];
        Wf1[idx + 2 * IN_F * HID_F] = 0.1f * c1[idx * 3 + 2];
    }
    if (idx < IN_F * OUT_F) {
        Wf2[idx]                    = w2[idx] + 0.1f * c2[idx * 3 + 0];
        Wf2[idx + IN_F * OUT_F]     = 0.1f * c2[idx * 3 + 1];
        Wf2[idx + 2 * IN_F * OUT_F] = 0.1f * c2[idx * 3 + 2];
    }
}

// ---------------------------------------------------------------------------
// CSR build: degree count -> 2-level exclusive scan -> slot fill.
// ---------------------------------------------------------------------------
__global__ __launch_bounds__(256) void deg_count(
    const int* __restrict__ tgt, int* __restrict__ deg, int n_edges)
{
    int e = blockIdx.x * 256 + threadIdx.x;
    if (e < n_edges) atomicAdd(&deg[tgt[e]], 1);
}

__global__ __launch_bounds__(256) void scan_bsum(
    const int* __restrict__ deg, int* __restrict__ bsum, int n)
{
    __shared__ int s[256];
    int tid = threadIdx.x;
    int i = blockIdx.x * 256 + tid;
    s[tid] = (i < n) ? deg[i] : 0;
    __syncthreads();
    for (int o = 128; o > 0; o >>= 1) {
        if (tid < o) s[tid] += s[tid + o];
        __syncthreads();
    }
    if (tid == 0) bsum[blockIdx.x] = s[0];
}

__global__ __launch_bounds__(512) void scan_top(int* __restrict__ bsum, int nb)
{
    __shared__ int s[512];
    int tid = threadIdx.x;
    int v = (tid < nb) ? bsum[tid] : 0;
    s[tid] = v;
    __syncthreads();
    for (int o = 1; o < 512; o <<= 1) {
        int t = (tid >= o) ? s[tid - o] : 0;
        __syncthreads();
        s[tid] += t;
        __syncthreads();
    }
    if (tid < nb) bsum[tid] = s[tid] - v;   // exclusive
}

__global__ __launch_bounds__(256) void scan_final(
    const int* __restrict__ deg, const int* __restrict__ bsum,
    int* __restrict__ row_start, int* __restrict__ cursor, int n)
{
    __shared__ int s[256];
    int tid = threadIdx.x;
    int i = blockIdx.x * 256 + tid;
    int v = (i < n) ? deg[i] : 0;
    s[tid] = v;
    __syncthreads();
    for (int o = 1; o < 256; o <<= 1) {
        int t = (tid >= o) ? s[tid - o] : 0;
        __syncthreads();
        s[tid] += t;
        __syncthreads();
    }
    int excl = s[tid] - v + bsum[blockIdx.x];
    if (i < n) { row_start[i] = excl; cursor[i] = excl; }
    if (i == n - 1) row_start[n] = excl + v;
}

__global__ __launch_bounds__(256) void csr_fill(
    const int* __restrict__ src, const int* __restrict__ tgt,
    int* __restrict__ cursor, int* __restrict__ csr_src, int n_edges)
{
    int e = blockIdx.x * 256 + threadIdx.x;
    if (e < n_edges) {
        int pos = atomicAdd(&cursor[tgt[e]], 1);
        csr_src[pos] = src[e];
    }
}

// ---------------------------------------------------------------------------
// KAN1 + ReLU.  Block = 4 waves = 32 nodes.  x rows staged in LDS (16 KB);
// inner-loop x reads are same-address LDS broadcasts (free, lgkm pipe)
// instead of high-latency global broadcasts.  lane -> outputs o, o+64.
// ---------------------------------------------------------------------------
__global__ __launch_bounds__(256) void kan1_kernel(
    const float* __restrict__ x, const float* __restrict__ Wf,
    const float* __restrict__ bias, float* __restrict__ h1)
{
    __shared__ float sx[32 * IN_F];   // 16 KB
    const int tid  = threadIdx.x;
    const int lane = tid & 63;
    const int wave = tid >> 6;
    const int nodeB = blockIdx.x * 32;

    // coalesced stage: 1024 float4 per block, 4 per thread
    const float4* xg = (const float4*)(x + (size_t)nodeB * IN_F);
    float4* sx4 = (float4*)sx;
#pragma unroll
    for (int i = 0; i < 4; ++i)
        sx4[tid + 256 * i] = xg[tid + 256 * i];
    __syncthreads();

    const float* W1 = Wf;
    const float* W2 = Wf + IN_F * HID_F;
    const float* W3 = Wf + 2 * IN_F * HID_F;
    const float* xs = sx + (wave * 8) * IN_F;

    float accA[8], accB[8];
#pragma unroll
    for (int j = 0; j < 8; ++j) { accA[j] = 0.f; accB[j] = 0.f; }

#pragma unroll 2
    for (int k = 0; k < IN_F; ++k) {
        float w1a = W1[k * HID_F + lane];
        float w1b = W1[k * HID_F + lane + 64];
        float w2a = W2[k * HID_F + lane];
        float w2b = W2[k * HID_F + lane + 64];
        float w3a = W3[k * HID_F + lane];
        float w3b = W3[k * HID_F + lane + 64];
#pragma unroll
        for (int j = 0; j < 8; ++j) {
            float xv = xs[j * IN_F + k];
            float x2 = xv * xv;
            float x3 = x2 * xv;
            accA[j] = fmaf(xv, w1a, fmaf(x2, w2a, fmaf(x3, w3a, accA[j])));
            accB[j] = fmaf(xv, w1b, fmaf(x2, w2b, fmaf(x3, w3b, accB[j])));
        }
    }

    const int node0 = nodeB + wave * 8;
    float ba = bias[lane], bb = bias[lane + 64];
#pragma unroll
    for (int j = 0; j < 8; ++j) {
        h1[(node0 + j) * HID_F + lane]      = fmaxf(accA[j] + ba, 0.f);
        h1[(node0 + j) * HID_F + lane + 64] = fmaxf(accB[j] + bb, 0.f);
    }
}

// ---------------------------------------------------------------------------
// KAN2: stages a1 rows into LDS with the 1/deg scaling applied at staging
// time (removes it from the inner loop entirely).
// ---------------------------------------------------------------------------
__global__ __launch_bounds__(256) void kan2_kernel(
    const float* __restrict__ a1, const int* __restrict__ deg,
    const float* __restrict__ Wf, const float* __restrict__ bias,
    float* __restrict__ h2)
{
    __shared__ float sx[32 * IN_F];   // 16 KB
    const int tid  = threadIdx.x;
    const int lane = tid & 63;
    const int wave = tid >> 6;
    const int nodeB = blockIdx.x * 32;

    const float4* xg = (const float4*)(a1 + (size_t)nodeB * IN_F);
    float4* sx4 = (float4*)sx;
#pragma unroll
    for (int i = 0; i < 4; ++i) {
        int f4 = tid + 256 * i;
        int row = f4 >> 5;                  // 32 float4 per row
        float di = 1.0f / fmaxf((float)deg[nodeB + row], 1.0f);
        float4 v = xg[f4];
        v.x *= di; v.y *= di; v.z *= di; v.w *= di;
        sx4[f4] = v;
    }
    __syncthreads();

    const float* W1 = Wf;
    const float* W2 = Wf + IN_F * OUT_F;
    const float* W3 = Wf + 2 * IN_F * OUT_F;
    const float* xs = sx + (wave * 8) * IN_F;

    float acc[8];
#pragma unroll
    for (int j = 0; j < 8; ++j) acc[j] = 0.f;

#pragma unroll 4
    for (int k = 0; k < IN_F; ++k) {
        float w1 = W1[k * OUT_F + lane];
        float w2 = W2[k * OUT_F + lane];
        float w3 = W3[k * OUT_F + lane];
#pragma unroll
        for (int j = 0; j < 8; ++j) {
            float xv = xs[j * IN_F + k];
            float x2 = xv * xv;
            float x3 = x2 * xv;
            acc[j] = fmaf(xv, w1, fmaf(x2, w2, fmaf(x3, w3, acc[j])));
        }
    }

    const int node0 = nodeB + wave * 8;
    float b = bias[lane];
#pragma unroll
    for (int j = 0; j < 8; ++j)
        h2[(node0 + j) * OUT_F + lane] = acc[j] + b;
}

// ---------------------------------------------------------------------------
// Gather-aggregate over 128 feats: one wave per node, lane holds float2.
// ---------------------------------------------------------------------------
__global__ __launch_bounds__(256) void gather128(
    const float* __restrict__ h, const int* __restrict__ row_start,
    const int* __restrict__ csr_src, float* __restrict__ out)
{
    const int lane = threadIdx.x & 63;
    const int wave = threadIdx.x >> 6;
    const int node = blockIdx.x * 4 + wave;
    if (node >= N_NODES) return;

    int e0 = row_start[node], e1 = row_start[node + 1];
    const float2* hp = (const float2*)h;
    float ax = 0.f, ay = 0.f;

    for (int base = e0; base < e1; base += 64) {
        int idx = base + lane;
        int sreg = (idx < e1) ? csr_src[idx] : 0;
        int cnt = min(64, e1 - base);
        for (int j = 0; j < cnt; ++j) {
            int sj = __shfl(sreg, j);
            float2 v = hp[sj * 64 + lane];
            ax += v.x; ay += v.y;
        }
    }
    float2 r; r.x = ax; r.y = ay;
    ((float2*)out)[node * 64 + lane] = r;
}

// ---------------------------------------------------------------------------
// Gather-aggregate over 64 feats fused with 1/deg + log_softmax.
// ---------------------------------------------------------------------------
__global__ __launch_bounds__(256) void gather64_lsm(
    const float* __restrict__ h, const int* __restrict__ row_start,
    const int* __restrict__ csr_src, const int* __restrict__ deg,
    float* __restrict__ out)
{
    const int lane = threadIdx.x & 63;
    const int wave = threadIdx.x >> 6;
    const int node = blockIdx.x * 4 + wave;
    if (node >= N_NODES) return;

    int e0 = row_start[node], e1 = row_start[node + 1];
    float acc = 0.f;

    for (int base = e0; base < e1; base += 64) {
        int idx = base + lane;
        int sreg = (idx < e1) ? csr_src[idx] : 0;
        int cnt = min(64, e1 - base);
        for (int j = 0; j < cnt; ++j) {
            int sj = __shfl(sreg, j);
            acc += h[sj * OUT_F + lane];
        }
    }

    float di = 1.0f / fmaxf((float)deg[node], 1.0f);
    float v = acc * di;

    float m = v;
#pragma unroll
    for (int off = 32; off >= 1; off >>= 1)
        m = fmaxf(m, __shfl_xor(m, off));
    float e = expf(v - m);
    float s = e;
#pragma unroll
    for (int off = 32; off >= 1; off >>= 1)
        s += __shfl_xor(s, off);
    out[node * OUT_F + lane] = v - m - logf(s);
}

// ---------------------------------------------------------------------------
extern "C" void kernel_launch(void* const* d_in, const int* in_sizes, int n_in,
                              void* d_out, int out_size, void* d_ws, size_t ws_size,
                              hipStream_t stream)
{
    const float* x  = (const float*)d_in[0];
    const int*   ei = (const int*)d_in[1];
    const float* w1 = (const float*)d_in[2];
    const float* b1 = (const float*)d_in[3];
    const float* c1 = (const float*)d_in[4];
    const float* w2 = (const float*)d_in[5];
    const float* b2 = (const float*)d_in[6];
    const float* c2 = (const float*)d_in[7];
    float* out = (float*)d_out;

    const int* src = ei;            // edge_index[0]
    const int* tgt = ei + N_EDGES;  // edge_index[1]

    char* ws = (char*)d_ws;
    size_t off = 0;
    auto carve = [&](size_t bytes) -> void* {
        void* p = ws + off;
        off = (off + bytes + 255) & ~(size_t)255;
        return p;
    };
    float* Wf1      = (float*)carve(3 * IN_F * HID_F * 4);
    float* Wf2      = (float*)carve(3 * IN_F * OUT_F * 4);
    int*   deg      = (int*)carve((size_t)N_NODES * 4);
    int*   row_start= (int*)carve(((size_t)N_NODES + 1) * 4);
    int*   cursor   = (int*)carve((size_t)N_NODES * 4);
    int*   bsum     = (int*)carve((size_t)NB_SCAN * 4);
    int*   csr_src  = (int*)carve((size_t)N_EDGES * 4);
    float* bufA     = (float*)carve((size_t)N_NODES * HID_F * 4);  // h1, then h2
    float* bufB     = (float*)carve((size_t)N_NODES * HID_F * 4);  // a1

    // --- CSR build -----------------------------------------------------------
    hipMemsetAsync(deg, 0, (size_t)N_NODES * 4, stream);
    deg_count<<<(N_EDGES + 255) / 256, 256, 0, stream>>>(tgt, deg, N_EDGES);
    scan_bsum<<<NB_SCAN, 256, 0, stream>>>(deg, bsum, N_NODES);
    scan_top<<<1, 512, 0, stream>>>(bsum, NB_SCAN);
    scan_final<<<NB_SCAN, 256, 0, stream>>>(deg, bsum, row_start, cursor, N_NODES);
    csr_fill<<<(N_EDGES + 255) / 256, 256, 0, stream>>>(src, tgt, cursor, csr_src, N_EDGES);

    // --- weights + layer 1 ---------------------------------------------------
    fold_weights<<<64, 256, 0, stream>>>(w1, c1, w2, c2, Wf1, Wf2);
    kan1_kernel<<<N_NODES / 32, 256, 0, stream>>>(x, Wf1, b1, bufA);

    // --- aggregate 1 (gather, no atomics) ------------------------------------
    gather128<<<(N_NODES + 3) / 4, 256, 0, stream>>>(bufA, row_start, csr_src, bufB);

    // --- layer 2 -------------------------------------------------------------
    kan2_kernel<<<N_NODES / 32, 256, 0, stream>>>(bufB, deg, Wf2, b2, bufA);

    // --- aggregate 2 + log_softmax (fused) -----------------------------------
    gather64_lsm<<<(N_NODES + 3) / 4, 256, 0, stream>>>(bufA, row_start, csr_src, deg, out);
}

// Round 4
// 554.531 us; speedup vs baseline: 8.4967x; 1.4090x over previous
//
#include <hip/hip_runtime.h>
#include <hip/hip_bf16.h>
#include <math.h>

#define N_NODES 100000
#define N_EDGES 1600000
#define IN_F 128
#define HID_F 128
#define OUT_F 64
#define K_TOT 384                          // 3 basis planes x 128
#define NB_SCAN ((N_NODES + 255) / 256)
#define XLDS_STRIDE 132                    // 128 + 4 pad -> conflict-free b128 reads

typedef __attribute__((ext_vector_type(8))) short s8v;   // 8 bf16 = 4 VGPRs (MFMA A/B frag)
typedef __attribute__((ext_vector_type(4))) float f4v;   // MFMA C/D frag

__device__ __forceinline__ short f2bf(float f) {
    __hip_bfloat16 h = __float2bfloat16(f);
    return __builtin_bit_cast(short, h);
}
__device__ __forceinline__ float bfhi2f(unsigned u) {   // high 16 bits as bf16
    return __builtin_bit_cast(float, u & 0xffff0000u);
}
__device__ __forceinline__ float bflo2f(unsigned u) {   // low 16 bits as bf16
    return __builtin_bit_cast(float, u << 16);
}

// ---------------------------------------------------------------------------
// Fold KAN weights into bf16 MFMA-B chunk layout: Wb[c][n][8], c = k>>3,
// k in [0,384): plane p=k>>7, f=k&127. plane0 = w + 0.1*c0, else 0.1*c_p.
// ---------------------------------------------------------------------------
__global__ __launch_bounds__(256) void fold_weights_bf16(
    const float* __restrict__ w1, const float* __restrict__ c1,
    const float* __restrict__ w2, const float* __restrict__ c2,
    short* __restrict__ Wb1, short* __restrict__ Wb2)
{
    int idx = blockIdx.x * 256 + threadIdx.x;
    if (idx < K_TOT * HID_F) {
        int k = idx >> 7, n = idx & 127;
        int p = k >> 7, f = k & 127;
        int si = f * HID_F + n;
        float v = (p == 0) ? (w1[si] + 0.1f * c1[si * 3])
                           : 0.1f * c1[si * 3 + p];
        Wb1[(((k >> 3) * HID_F) + n) * 8 + (k & 7)] = f2bf(v);
    } else {
        idx -= K_TOT * HID_F;
        if (idx < K_TOT * OUT_F) {
            int k = idx >> 6, n = idx & 63;
            int p = k >> 7, f = k & 127;
            int si = f * OUT_F + n;
            float v = (p == 0) ? (w2[si] + 0.1f * c2[si * 3])
                               : 0.1f * c2[si * 3 + p];
            Wb2[(((k >> 3) * OUT_F) + n) * 8 + (k & 7)] = f2bf(v);
        }
    }
}

// ---------------------------------------------------------------------------
// CSR build: degree count -> 2-level exclusive scan -> slot fill.
// ---------------------------------------------------------------------------
__global__ __launch_bounds__(256) void deg_count(
    const int* __restrict__ tgt, int* __restrict__ deg, int n_edges)
{
    int e = blockIdx.x * 256 + threadIdx.x;
    if (e < n_edges) atomicAdd(&deg[tgt[e]], 1);
}

__global__ __launch_bounds__(256) void scan_bsum(
    const int* __restrict__ deg, int* __restrict__ bsum, int n)
{
    __shared__ int s[256];
    int tid = threadIdx.x;
    int i = blockIdx.x * 256 + tid;
    s[tid] = (i < n) ? deg[i] : 0;
    __syncthreads();
    for (int o = 128; o > 0; o >>= 1) {
        if (tid < o) s[tid] += s[tid + o];
        __syncthreads();
    }
    if (tid == 0) bsum[blockIdx.x] = s[0];
}

__global__ __launch_bounds__(512) void scan_top(int* __restrict__ bsum, int nb)
{
    __shared__ int s[512];
    int tid = threadIdx.x;
    int v = (tid < nb) ? bsum[tid] : 0;
    s[tid] = v;
    __syncthreads();
    for (int o = 1; o < 512; o <<= 1) {
        int t = (tid >= o) ? s[tid - o] : 0;
        __syncthreads();
        s[tid] += t;
        __syncthreads();
    }
    if (tid < nb) bsum[tid] = s[tid] - v;   // exclusive
}

__global__ __launch_bounds__(256) void scan_final(
    const int* __restrict__ deg, const int* __restrict__ bsum,
    int* __restrict__ row_start, int* __restrict__ cursor, int n)
{
    __shared__ int s[256];
    int tid = threadIdx.x;
    int i = blockIdx.x * 256 + tid;
    int v = (i < n) ? deg[i] : 0;
    s[tid] = v;
    __syncthreads();
    for (int o = 1; o < 256; o <<= 1) {
        int t = (tid >= o) ? s[tid - o] : 0;
        __syncthreads();
        s[tid] += t;
        __syncthreads();
    }
    int excl = s[tid] - v + bsum[blockIdx.x];
    if (i < n) { row_start[i] = excl; cursor[i] = excl; }
    if (i == n - 1) row_start[n] = excl + v;
}

__global__ __launch_bounds__(256) void csr_fill(
    const int* __restrict__ src, const int* __restrict__ tgt,
    int* __restrict__ cursor, int* __restrict__ csr_src, int n_edges)
{
    int e = blockIdx.x * 256 + threadIdx.x;
    if (e < n_edges) {
        int pos = atomicAdd(&cursor[tgt[e]], 1);
        csr_src[pos] = src[e];
    }
}

// ---------------------------------------------------------------------------
// KAN1 via MFMA bf16: block = 64 nodes x 128 out, 4 waves tiled 2x2 (32x64).
// x tile staged fp32 in LDS; basis plane (x / x^2 / x^3) computed in regs
// per k-chunk (plane = kb>>2, compile-time).  B frags straight from global
// (chunk layout, coalesced, L2-hot).  Epilogue: +bias, ReLU, bf16 store.
// ---------------------------------------------------------------------------
__global__ __launch_bounds__(256) void kan1_mfma(
    const float* __restrict__ x, const short* __restrict__ Wb,
    const float* __restrict__ bias, short* __restrict__ h1)
{
    __shared__ float sx[64 * XLDS_STRIDE];
    const int tid  = threadIdx.x;
    const int lane = tid & 63;
    const int wave = tid >> 6;
    const int node0 = blockIdx.x * 64;
    const int q = lane >> 4, r = lane & 15;

    // stage x tile (coalesced float4; clamp rows for the tail block)
#pragma unroll
    for (int it = 0; it < 8; ++it) {
        int idx = tid + 256 * it;            // 0..2047 = 64 rows x 32 float4
        int m = idx >> 5, c4 = (idx & 31) * 4;
        int gm = min(node0 + m, N_NODES - 1);
        float4 v = *(const float4*)(x + (size_t)gm * IN_F + c4);
        *(float4*)(sx + m * XLDS_STRIDE + c4) = v;
    }
    __syncthreads();

    const int wm = (wave & 1) * 32;          // wave row offset in tile
    const int wn = (wave >> 1) * 64;         // wave col offset

    f4v acc[2][4];
#pragma unroll
    for (int i = 0; i < 2; ++i)
#pragma unroll
        for (int j = 0; j < 4; ++j)
            acc[i][j] = (f4v){0.f, 0.f, 0.f, 0.f};

    float bj[4];
#pragma unroll
    for (int j = 0; j < 4; ++j) bj[j] = bias[wn + j * 16 + r];

#pragma unroll
    for (int kb = 0; kb < 12; ++kb) {
        const int p  = kb >> 2;              // basis plane (compile-time)
        const int f0 = (kb & 3) * 32 + q * 8;

        s8v afrag[2];
#pragma unroll
        for (int i = 0; i < 2; ++i) {
            const float* xs = sx + (wm + i * 16 + r) * XLDS_STRIDE + f0;
            float4 v0 = *(const float4*)xs;
            float4 v1 = *(const float4*)(xs + 4);
            float v[8] = {v0.x, v0.y, v0.z, v0.w, v1.x, v1.y, v1.z, v1.w};
            s8v a;
#pragma unroll
            for (int t = 0; t < 8; ++t) {
                float e = v[t];
                if (p >= 1) e *= v[t];
                if (p == 2) e *= v[t];
                a[t] = f2bf(e);
            }
            afrag[i] = a;
        }
#pragma unroll
        for (int j = 0; j < 4; ++j) {
            const s8v b = *(const s8v*)(Wb + (((kb * 4 + q) * HID_F) + wn + j * 16 + r) * 8);
            acc[0][j] = __builtin_amdgcn_mfma_f32_16x16x32_bf16(afrag[0], b, acc[0][j], 0, 0, 0);
            acc[1][j] = __builtin_amdgcn_mfma_f32_16x16x32_bf16(afrag[1], b, acc[1][j], 0, 0, 0);
        }
    }

    // epilogue: D[row=q*4+e][col=r] per 16x16 frag
#pragma unroll
    for (int i = 0; i < 2; ++i)
#pragma unroll
        for (int j = 0; j < 4; ++j)
#pragma unroll
            for (int e = 0; e < 4; ++e) {
                int grow = node0 + wm + i * 16 + q * 4 + e;
                if (grow < N_NODES) {
                    int gcol = wn + j * 16 + r;
                    h1[(size_t)grow * HID_F + gcol] =
                        f2bf(fmaxf(acc[i][j][e] + bj[j], 0.f));
                }
            }
}

// ---------------------------------------------------------------------------
// KAN2 via MFMA bf16: block = 64 nodes x 64 out, 4 waves tiled 2x2 (32x32).
// 1/deg fused into the fp32 LDS staging of a1.  No ReLU.
// ---------------------------------------------------------------------------
__global__ __launch_bounds__(256) void kan2_mfma(
    const float* __restrict__ a1, const int* __restrict__ deg,
    const short* __restrict__ Wb, const float* __restrict__ bias,
    short* __restrict__ h2)
{
    __shared__ float sx[64 * XLDS_STRIDE];
    const int tid  = threadIdx.x;
    const int lane = tid & 63;
    const int wave = tid >> 6;
    const int node0 = blockIdx.x * 64;
    const int q = lane >> 4, r = lane & 15;

#pragma unroll
    for (int it = 0; it < 8; ++it) {
        int idx = tid + 256 * it;
        int m = idx >> 5, c4 = (idx & 31) * 4;
        int gm = min(node0 + m, N_NODES - 1);
        float di = 1.0f / fmaxf((float)deg[gm], 1.0f);
        float4 v = *(const float4*)(a1 + (size_t)gm * IN_F + c4);
        v.x *= di; v.y *= di; v.z *= di; v.w *= di;
        *(float4*)(sx + m * XLDS_STRIDE + c4) = v;
    }
    __syncthreads();

    const int wm = (wave & 1) * 32;
    const int wn = (wave >> 1) * 32;

    f4v acc[2][2];
#pragma unroll
    for (int i = 0; i < 2; ++i)
#pragma unroll
        for (int j = 0; j < 2; ++j)
            acc[i][j] = (f4v){0.f, 0.f, 0.f, 0.f};

    float bj[2];
#pragma unroll
    for (int j = 0; j < 2; ++j) bj[j] = bias[wn + j * 16 + r];

#pragma unroll
    for (int kb = 0; kb < 12; ++kb) {
        const int p  = kb >> 2;
        const int f0 = (kb & 3) * 32 + q * 8;

        s8v afrag[2];
#pragma unroll
        for (int i = 0; i < 2; ++i) {
            const float* xs = sx + (wm + i * 16 + r) * XLDS_STRIDE + f0;
            float4 v0 = *(const float4*)xs;
            float4 v1 = *(const float4*)(xs + 4);
            float v[8] = {v0.x, v0.y, v0.z, v0.w, v1.x, v1.y, v1.z, v1.w};
            s8v a;
#pragma unroll
            for (int t = 0; t < 8; ++t) {
                float e = v[t];
                if (p >= 1) e *= v[t];
                if (p == 2) e *= v[t];
                a[t] = f2bf(e);
            }
            afrag[i] = a;
        }
#pragma unroll
        for (int j = 0; j < 2; ++j) {
            const s8v b = *(const s8v*)(Wb + (((kb * 4 + q) * OUT_F) + wn + j * 16 + r) * 8);
            acc[0][j] = __builtin_amdgcn_mfma_f32_16x16x32_bf16(afrag[0], b, acc[0][j], 0, 0, 0);
            acc[1][j] = __builtin_amdgcn_mfma_f32_16x16x32_bf16(afrag[1], b, acc[1][j], 0, 0, 0);
        }
    }

#pragma unroll
    for (int i = 0; i < 2; ++i)
#pragma unroll
        for (int j = 0; j < 2; ++j)
#pragma unroll
            for (int e = 0; e < 4; ++e) {
                int grow = node0 + wm + i * 16 + q * 4 + e;
                if (grow < N_NODES) {
                    int gcol = wn + j * 16 + r;
                    h2[(size_t)grow * OUT_F + gcol] = f2bf(acc[i][j][e] + bj[j]);
                }
            }
}

// ---------------------------------------------------------------------------
// Gather-aggregate over 128 bf16 feats -> fp32 out.  Wave per node; lane
// holds a bf16x2 (4 B) -> 256 B per message, coalesced.
// ---------------------------------------------------------------------------
__global__ __launch_bounds__(256) void gather128(
    const unsigned* __restrict__ h1u, const int* __restrict__ row_start,
    const int* __restrict__ csr_src, float* __restrict__ out)
{
    const int lane = threadIdx.x & 63;
    const int wave = threadIdx.x >> 6;
    const int node = blockIdx.x * 4 + wave;
    if (node >= N_NODES) return;

    int e0 = row_start[node], e1 = row_start[node + 1];
    float ax = 0.f, ay = 0.f;

    for (int base = e0; base < e1; base += 64) {
        int idx = base + lane;
        int sreg = (idx < e1) ? csr_src[idx] : 0;
        int cnt = min(64, e1 - base);
        for (int j = 0; j < cnt; ++j) {
            int sj = __shfl(sreg, j);
            unsigned u = h1u[(size_t)sj * 64 + lane];
            ax += bflo2f(u);
            ay += bfhi2f(u);
        }
    }
    float2 rv; rv.x = ax; rv.y = ay;
    ((float2*)out)[(size_t)node * 64 + lane] = rv;
}

// ---------------------------------------------------------------------------
// Gather-aggregate over 64 bf16 feats fused with 1/deg + log_softmax.
// ---------------------------------------------------------------------------
__global__ __launch_bounds__(256) void gather64_lsm(
    const unsigned short* __restrict__ h2u, const int* __restrict__ row_start,
    const int* __restrict__ csr_src, const int* __restrict__ deg,
    float* __restrict__ out)
{
    const int lane = threadIdx.x & 63;
    const int wave = threadIdx.x >> 6;
    const int node = blockIdx.x * 4 + wave;
    if (node >= N_NODES) return;

    int e0 = row_start[node], e1 = row_start[node + 1];
    float acc = 0.f;

    for (int base = e0; base < e1; base += 64) {
        int idx = base + lane;
        int sreg = (idx < e1) ? csr_src[idx] : 0;
        int cnt = min(64, e1 - base);
        for (int j = 0; j < cnt; ++j) {
            int sj = __shfl(sreg, j);
            acc += bflo2f((unsigned)h2u[(size_t)sj * OUT_F + lane]);
        }
    }

    float di = 1.0f / fmaxf((float)deg[node], 1.0f);
    float v = acc * di;

    float m = v;
#pragma unroll
    for (int off = 32; off >= 1; off >>= 1)
        m = fmaxf(m, __shfl_xor(m, off));
    float e = expf(v - m);
    float s = e;
#pragma unroll
    for (int off = 32; off >= 1; off >>= 1)
        s += __shfl_xor(s, off);
    out[(size_t)node * OUT_F + lane] = v - m - logf(s);
}

// ---------------------------------------------------------------------------
extern "C" void kernel_launch(void* const* d_in, const int* in_sizes, int n_in,
                              void* d_out, int out_size, void* d_ws, size_t ws_size,
                              hipStream_t stream)
{
    const float* x  = (const float*)d_in[0];
    const int*   ei = (const int*)d_in[1];
    const float* w1 = (const float*)d_in[2];
    const float* b1 = (const float*)d_in[3];
    const float* c1 = (const float*)d_in[4];
    const float* w2 = (const float*)d_in[5];
    const float* b2 = (const float*)d_in[6];
    const float* c2 = (const float*)d_in[7];
    float* out = (float*)d_out;

    const int* src = ei;            // edge_index[0]
    const int* tgt = ei + N_EDGES;  // edge_index[1]

    char* ws = (char*)d_ws;
    size_t off = 0;
    auto carve = [&](size_t bytes) -> void* {
        void* p = ws + off;
        off = (off + bytes + 255) & ~(size_t)255;
        return p;
    };
    short* Wb1      = (short*)carve((size_t)K_TOT * HID_F * 2);
    short* Wb2      = (short*)carve((size_t)K_TOT * OUT_F * 2);
    int*   deg      = (int*)carve((size_t)N_NODES * 4);
    int*   row_start= (int*)carve(((size_t)N_NODES + 1) * 4);
    int*   cursor   = (int*)carve((size_t)N_NODES * 4);
    int*   bsum     = (int*)carve((size_t)NB_SCAN * 4);
    int*   csr_src  = (int*)carve((size_t)N_EDGES * 4);
    short* h1       = (short*)carve((size_t)N_NODES * HID_F * 2);   // bf16
    float* a1       = (float*)carve((size_t)N_NODES * IN_F * 4);    // fp32
    short* h2       = (short*)carve((size_t)N_NODES * OUT_F * 2);   // bf16

    const int grid_mm = (N_NODES + 63) / 64;   // 1563

    // --- CSR build -----------------------------------------------------------
    hipMemsetAsync(deg, 0, (size_t)N_NODES * 4, stream);
    deg_count<<<(N_EDGES + 255) / 256, 256, 0, stream>>>(tgt, deg, N_EDGES);
    scan_bsum<<<NB_SCAN, 256, 0, stream>>>(deg, bsum, N_NODES);
    scan_top<<<1, 512, 0, stream>>>(bsum, NB_SCAN);
    scan_final<<<NB_SCAN, 256, 0, stream>>>(deg, bsum, row_start, cursor, N_NODES);
    csr_fill<<<(N_EDGES + 255) / 256, 256, 0, stream>>>(src, tgt, cursor, csr_src, N_EDGES);

    // --- weights + layer 1 ---------------------------------------------------
    fold_weights_bf16<<<(K_TOT * HID_F + K_TOT * OUT_F + 255) / 256, 256, 0, stream>>>(
        w1, c1, w2, c2, Wb1, Wb2);
    kan1_mfma<<<grid_mm, 256, 0, stream>>>(x, Wb1, b1, h1);

    // --- aggregate 1 (gather, no atomics) ------------------------------------
    gather128<<<(N_NODES + 3) / 4, 256, 0, stream>>>((const unsigned*)h1, row_start, csr_src, a1);

    // --- layer 2 -------------------------------------------------------------
    kan2_mfma<<<grid_mm, 256, 0, stream>>>(a1, deg, Wb2, b2, h2);

    // --- aggregate 2 + log_softmax (fused) -----------------------------------
    gather64_lsm<<<(N_NODES + 3) / 4, 256, 0, stream>>>(
        (const unsigned short*)h2, row_start, csr_src, deg, out);
}

// Round 5
// 450.555 us; speedup vs baseline: 10.4575x; 1.2308x over previous
//
#include <hip/hip_runtime.h>
#include <hip/hip_bf16.h>
#include <math.h>

#define N_NODES 100000
#define N_EDGES 1600000
#define IN_F 128
#define HID_F 128
#define OUT_F 64
#define K_TOT 384                          // 3 basis planes x 128
#define NB_SCAN ((N_NODES + 255) / 256)    // 391
#define XLDS_STRIDE 132                    // 128 + 4 pad -> conflict-free b128 reads

// bucket sort parameters
#define BK_BITS 9
#define BK_SIZE 512                        // nodes per bucket
#define NBUCK ((N_NODES + BK_SIZE - 1) / BK_SIZE)   // 196
#define EPB 4096                           // edges per sort block
#define NBLK_SORT ((N_EDGES + EPB - 1) / EPB)       // 391

typedef __attribute__((ext_vector_type(8))) short s8v;   // 8 bf16 (MFMA A/B frag)
typedef __attribute__((ext_vector_type(4))) float f4v;   // MFMA C/D frag

__device__ __forceinline__ short f2bf(float f) {
    __hip_bfloat16 h = __float2bfloat16(f);
    return __builtin_bit_cast(short, h);
}
__device__ __forceinline__ float bfhi2f(unsigned u) {
    return __builtin_bit_cast(float, u & 0xffff0000u);
}
__device__ __forceinline__ float bflo2f(unsigned u) {
    return __builtin_bit_cast(float, u << 16);
}

// ---------------------------------------------------------------------------
// Fold KAN weights into bf16 MFMA-B chunk layout: Wb[c][n][8], c = k>>3.
// ---------------------------------------------------------------------------
__global__ __launch_bounds__(256) void fold_weights_bf16(
    const float* __restrict__ w1, const float* __restrict__ c1,
    const float* __restrict__ w2, const float* __restrict__ c2,
    short* __restrict__ Wb1, short* __restrict__ Wb2)
{
    int idx = blockIdx.x * 256 + threadIdx.x;
    if (idx < K_TOT * HID_F) {
        int k = idx >> 7, n = idx & 127;
        int p = k >> 7, f = k & 127;
        int si = f * HID_F + n;
        float v = (p == 0) ? (w1[si] + 0.1f * c1[si * 3])
                           : 0.1f * c1[si * 3 + p];
        Wb1[(((k >> 3) * HID_F) + n) * 8 + (k & 7)] = f2bf(v);
    } else {
        idx -= K_TOT * HID_F;
        if (idx < K_TOT * OUT_F) {
            int k = idx >> 6, n = idx & 63;
            int p = k >> 7, f = k & 127;
            int si = f * OUT_F + n;
            float v = (p == 0) ? (w2[si] + 0.1f * c2[si * 3])
                               : 0.1f * c2[si * 3 + p];
            Wb2[(((k >> 3) * OUT_F) + n) * 8 + (k & 7)] = f2bf(v);
        }
    }
}

// ---------------------------------------------------------------------------
// Bucket sort pass A: coarse histogram (LDS) -> global bucket counts.
// ---------------------------------------------------------------------------
__global__ __launch_bounds__(256) void bucket_hist(
    const int* __restrict__ tgt, int* __restrict__ bucket_cnt)
{
    __shared__ int h[NBUCK];
    int tid = threadIdx.x;
    for (int i = tid; i < NBUCK; i += 256) h[i] = 0;
    __syncthreads();
    int e0 = blockIdx.x * EPB;
    int n = min(EPB, N_EDGES - e0);
    for (int i = tid; i < n; i += 256)
        atomicAdd(&h[tgt[e0 + i] >> BK_BITS], 1);
    __syncthreads();
    for (int i = tid; i < NBUCK; i += 256)
        if (h[i]) atomicAdd(&bucket_cnt[i], h[i]);
}

// Pass B: single-block exclusive scan of bucket counts -> offsets + cursors.
__global__ __launch_bounds__(256) void bucket_scan(
    const int* __restrict__ cnt, int* __restrict__ boff, int* __restrict__ bcur)
{
    __shared__ int s[256];
    int tid = threadIdx.x;
    int v = (tid < NBUCK) ? cnt[tid] : 0;
    s[tid] = v;
    __syncthreads();
    for (int o = 1; o < 256; o <<= 1) {
        int t = (tid >= o) ? s[tid - o] : 0;
        __syncthreads();
        s[tid] += t;
        __syncthreads();
    }
    int excl = s[tid] - v;
    if (tid < NBUCK) { boff[tid] = excl; bcur[tid] = excl; }
    if (tid == NBUCK - 1) boff[NBUCK] = excl + v;
}

// Pass C: scatter edges into bucket-sorted (tgt,src) arrays.  Each
// (block,bucket) group claims a contiguous range once, then writes its
// ~21 entries contiguously -> no line-level write amplification.
__global__ __launch_bounds__(256) void bucket_scatter(
    const int* __restrict__ src, const int* __restrict__ tgt,
    int* __restrict__ bcur, int* __restrict__ skey, int* __restrict__ sval)
{
    __shared__ int h[NBUCK];
    __shared__ int base[NBUCK];
    int tid = threadIdx.x;
    for (int i = tid; i < NBUCK; i += 256) h[i] = 0;
    __syncthreads();
    int e0 = blockIdx.x * EPB;
    int n = min(EPB, N_EDGES - e0);
    for (int i = tid; i < n; i += 256)
        atomicAdd(&h[tgt[e0 + i] >> BK_BITS], 1);
    __syncthreads();
    for (int i = tid; i < NBUCK; i += 256) {
        int c = h[i];
        base[i] = c ? atomicAdd(&bcur[i], c) : 0;
        h[i] = 0;
    }
    __syncthreads();
    for (int i = tid; i < n; i += 256) {
        int t = tgt[e0 + i];
        int b = t >> BK_BITS;
        int pos = base[b] + atomicAdd(&h[b], 1);
        skey[pos] = t;
        sval[pos] = src[e0 + i];
    }
}

// Pass D: per-bucket degree via LDS histogram (replaces global deg_count).
__global__ __launch_bounds__(256) void bucket_deg(
    const int* __restrict__ boff, const int* __restrict__ skey,
    int* __restrict__ deg)
{
    __shared__ int d[BK_SIZE];
    int tid = threadIdx.x;
    int b = blockIdx.x;
    for (int i = tid; i < BK_SIZE; i += 256) d[i] = 0;
    __syncthreads();
    int e0 = boff[b], e1 = boff[b + 1];
    int nbase = b << BK_BITS;
    for (int i = e0 + tid; i < e1; i += 256)
        atomicAdd(&d[skey[i] - nbase], 1);
    __syncthreads();
    for (int i = tid; i < BK_SIZE; i += 256) {
        int nd = nbase + i;
        if (nd < N_NODES) deg[nd] = d[i];
    }
}

// ---------------------------------------------------------------------------
// row_start scan over deg (3-kernel, unchanged structure).
// ---------------------------------------------------------------------------
__global__ __launch_bounds__(256) void scan_bsum(
    const int* __restrict__ deg, int* __restrict__ bsum, int n)
{
    __shared__ int s[256];
    int tid = threadIdx.x;
    int i = blockIdx.x * 256 + tid;
    s[tid] = (i < n) ? deg[i] : 0;
    __syncthreads();
    for (int o = 128; o > 0; o >>= 1) {
        if (tid < o) s[tid] += s[tid + o];
        __syncthreads();
    }
    if (tid == 0) bsum[blockIdx.x] = s[0];
}

__global__ __launch_bounds__(512) void scan_top(int* __restrict__ bsum, int nb)
{
    __shared__ int s[512];
    int tid = threadIdx.x;
    int v = (tid < nb) ? bsum[tid] : 0;
    s[tid] = v;
    __syncthreads();
    for (int o = 1; o < 512; o <<= 1) {
        int t = (tid >= o) ? s[tid - o] : 0;
        __syncthreads();
        s[tid] += t;
        __syncthreads();
    }
    if (tid < nb) bsum[tid] = s[tid] - v;   // exclusive
}

__global__ __launch_bounds__(256) void scan_final(
    const int* __restrict__ deg, const int* __restrict__ bsum,
    int* __restrict__ row_start, int n)
{
    __shared__ int s[256];
    int tid = threadIdx.x;
    int i = blockIdx.x * 256 + tid;
    int v = (i < n) ? deg[i] : 0;
    s[tid] = v;
    __syncthreads();
    for (int o = 1; o < 256; o <<= 1) {
        int t = (tid >= o) ? s[tid - o] : 0;
        __syncthreads();
        s[tid] += t;
        __syncthreads();
    }
    int excl = s[tid] - v + bsum[blockIdx.x];
    if (i < n) row_start[i] = excl;
    if (i == n - 1) row_start[n] = excl + v;
}

// Pass E: fine CSR fill.  One block per bucket; LDS cursors seeded from
// row_start; csr writes land in one contiguous ~32 KB window per block.
__global__ __launch_bounds__(256) void csr_fine(
    const int* __restrict__ boff, const int* __restrict__ skey,
    const int* __restrict__ sval, const int* __restrict__ row_start,
    int* __restrict__ csr_src)
{
    __shared__ int cur[BK_SIZE];
    int tid = threadIdx.x;
    int b = blockIdx.x;
    int nbase = b << BK_BITS;
    for (int i = tid; i < BK_SIZE; i += 256) {
        int nd = nbase + i;
        cur[i] = (nd < N_NODES) ? row_start[nd] : 0;
    }
    __syncthreads();
    int e0 = boff[b], e1 = boff[b + 1];
    for (int i = e0 + tid; i < e1; i += 256) {
        int pos = atomicAdd(&cur[skey[i] - nbase], 1);
        csr_src[pos] = sval[i];
    }
}

// ---------------------------------------------------------------------------
// KAN1 via MFMA bf16 (block = 64 nodes x 128 out, 4 waves 2x2).
// ---------------------------------------------------------------------------
__global__ __launch_bounds__(256) void kan1_mfma(
    const float* __restrict__ x, const short* __restrict__ Wb,
    const float* __restrict__ bias, short* __restrict__ h1)
{
    __shared__ float sx[64 * XLDS_STRIDE];
    const int tid  = threadIdx.x;
    const int lane = tid & 63;
    const int wave = tid >> 6;
    const int node0 = blockIdx.x * 64;
    const int q = lane >> 4, r = lane & 15;

#pragma unroll
    for (int it = 0; it < 8; ++it) {
        int idx = tid + 256 * it;
        int m = idx >> 5, c4 = (idx & 31) * 4;
        int gm = min(node0 + m, N_NODES - 1);
        float4 v = *(const float4*)(x + (size_t)gm * IN_F + c4);
        *(float4*)(sx + m * XLDS_STRIDE + c4) = v;
    }
    __syncthreads();

    const int wm = (wave & 1) * 32;
    const int wn = (wave >> 1) * 64;

    f4v acc[2][4];
#pragma unroll
    for (int i = 0; i < 2; ++i)
#pragma unroll
        for (int j = 0; j < 4; ++j)
            acc[i][j] = (f4v){0.f, 0.f, 0.f, 0.f};

    float bj[4];
#pragma unroll
    for (int j = 0; j < 4; ++j) bj[j] = bias[wn + j * 16 + r];

#pragma unroll
    for (int kb = 0; kb < 12; ++kb) {
        const int p  = kb >> 2;
        const int f0 = (kb & 3) * 32 + q * 8;

        s8v afrag[2];
#pragma unroll
        for (int i = 0; i < 2; ++i) {
            const float* xs = sx + (wm + i * 16 + r) * XLDS_STRIDE + f0;
            float4 v0 = *(const float4*)xs;
            float4 v1 = *(const float4*)(xs + 4);
            float v[8] = {v0.x, v0.y, v0.z, v0.w, v1.x, v1.y, v1.z, v1.w};
            s8v a;
#pragma unroll
            for (int t = 0; t < 8; ++t) {
                float e = v[t];
                if (p >= 1) e *= v[t];
                if (p == 2) e *= v[t];
                a[t] = f2bf(e);
            }
            afrag[i] = a;
        }
#pragma unroll
        for (int j = 0; j < 4; ++j) {
            const s8v b = *(const s8v*)(Wb + (((kb * 4 + q) * HID_F) + wn + j * 16 + r) * 8);
            acc[0][j] = __builtin_amdgcn_mfma_f32_16x16x32_bf16(afrag[0], b, acc[0][j], 0, 0, 0);
            acc[1][j] = __builtin_amdgcn_mfma_f32_16x16x32_bf16(afrag[1], b, acc[1][j], 0, 0, 0);
        }
    }

#pragma unroll
    for (int i = 0; i < 2; ++i)
#pragma unroll
        for (int j = 0; j < 4; ++j)
#pragma unroll
            for (int e = 0; e < 4; ++e) {
                int grow = node0 + wm + i * 16 + q * 4 + e;
                if (grow < N_NODES) {
                    int gcol = wn + j * 16 + r;
                    h1[(size_t)grow * HID_F + gcol] =
                        f2bf(fmaxf(acc[i][j][e] + bj[j], 0.f));
                }
            }
}

// ---------------------------------------------------------------------------
// KAN2 via MFMA bf16 (block = 64 nodes x 64 out); 1/deg fused at staging.
// ---------------------------------------------------------------------------
__global__ __launch_bounds__(256) void kan2_mfma(
    const float* __restrict__ a1, const int* __restrict__ deg,
    const short* __restrict__ Wb, const float* __restrict__ bias,
    short* __restrict__ h2)
{
    __shared__ float sx[64 * XLDS_STRIDE];
    const int tid  = threadIdx.x;
    const int lane = tid & 63;
    const int wave = tid >> 6;
    const int node0 = blockIdx.x * 64;
    const int q = lane >> 4, r = lane & 15;

#pragma unroll
    for (int it = 0; it < 8; ++it) {
        int idx = tid + 256 * it;
        int m = idx >> 5, c4 = (idx & 31) * 4;
        int gm = min(node0 + m, N_NODES - 1);
        float di = 1.0f / fmaxf((float)deg[gm], 1.0f);
        float4 v = *(const float4*)(a1 + (size_t)gm * IN_F + c4);
        v.x *= di; v.y *= di; v.z *= di; v.w *= di;
        *(float4*)(sx + m * XLDS_STRIDE + c4) = v;
    }
    __syncthreads();

    const int wm = (wave & 1) * 32;
    const int wn = (wave >> 1) * 32;

    f4v acc[2][2];
#pragma unroll
    for (int i = 0; i < 2; ++i)
#pragma unroll
        for (int j = 0; j < 2; ++j)
            acc[i][j] = (f4v){0.f, 0.f, 0.f, 0.f};

    float bj[2];
#pragma unroll
    for (int j = 0; j < 2; ++j) bj[j] = bias[wn + j * 16 + r];

#pragma unroll
    for (int kb = 0; kb < 12; ++kb) {
        const int p  = kb >> 2;
        const int f0 = (kb & 3) * 32 + q * 8;

        s8v afrag[2];
#pragma unroll
        for (int i = 0; i < 2; ++i) {
            const float* xs = sx + (wm + i * 16 + r) * XLDS_STRIDE + f0;
            float4 v0 = *(const float4*)xs;
            float4 v1 = *(const float4*)(xs + 4);
            float v[8] = {v0.x, v0.y, v0.z, v0.w, v1.x, v1.y, v1.z, v1.w};
            s8v a;
#pragma unroll
            for (int t = 0; t < 8; ++t) {
                float e = v[t];
                if (p >= 1) e *= v[t];
                if (p == 2) e *= v[t];
                a[t] = f2bf(e);
            }
            afrag[i] = a;
        }
#pragma unroll
        for (int j = 0; j < 2; ++j) {
            const s8v b = *(const s8v*)(Wb + (((kb * 4 + q) * OUT_F) + wn + j * 16 + r) * 8);
            acc[0][j] = __builtin_amdgcn_mfma_f32_16x16x32_bf16(afrag[0], b, acc[0][j], 0, 0, 0);
            acc[1][j] = __builtin_amdgcn_mfma_f32_16x16x32_bf16(afrag[1], b, acc[1][j], 0, 0, 0);
        }
    }

#pragma unroll
    for (int i = 0; i < 2; ++i)
#pragma unroll
        for (int j = 0; j < 2; ++j)
#pragma unroll
            for (int e = 0; e < 4; ++e) {
                int grow = node0 + wm + i * 16 + q * 4 + e;
                if (grow < N_NODES) {
                    int gcol = wn + j * 16 + r;
                    h2[(size_t)grow * OUT_F + gcol] = f2bf(acc[i][j][e] + bj[j]);
                }
            }
}

// ---------------------------------------------------------------------------
// Gather-aggregate over 128 bf16 feats -> fp32 out.
// ---------------------------------------------------------------------------
__global__ __launch_bounds__(256) void gather128(
    const unsigned* __restrict__ h1u, const int* __restrict__ row_start,
    const int* __restrict__ csr_src, float* __restrict__ out)
{
    const int lane = threadIdx.x & 63;
    const int wave = threadIdx.x >> 6;
    const int node = blockIdx.x * 4 + wave;
    if (node >= N_NODES) return;

    int e0 = row_start[node], e1 = row_start[node + 1];
    float ax = 0.f, ay = 0.f;

    for (int base = e0; base < e1; base += 64) {
        int idx = base + lane;
        int sreg = (idx < e1) ? csr_src[idx] : 0;
        int cnt = min(64, e1 - base);
        for (int j = 0; j < cnt; ++j) {
            int sj = __shfl(sreg, j);
            unsigned u = h1u[(size_t)sj * 64 + lane];
            ax += bflo2f(u);
            ay += bfhi2f(u);
        }
    }
    float2 rv; rv.x = ax; rv.y = ay;
    ((float2*)out)[(size_t)node * 64 + lane] = rv;
}

// ---------------------------------------------------------------------------
// Gather-aggregate over 64 bf16 feats fused with 1/deg + log_softmax.
// ---------------------------------------------------------------------------
__global__ __launch_bounds__(256) void gather64_lsm(
    const unsigned short* __restrict__ h2u, const int* __restrict__ row_start,
    const int* __restrict__ csr_src, const int* __restrict__ deg,
    float* __restrict__ out)
{
    const int lane = threadIdx.x & 63;
    const int wave = threadIdx.x >> 6;
    const int node = blockIdx.x * 4 + wave;
    if (node >= N_NODES) return;

    int e0 = row_start[node], e1 = row_start[node + 1];
    float acc = 0.f;

    for (int base = e0; base < e1; base += 64) {
        int idx = base + lane;
        int sreg = (idx < e1) ? csr_src[idx] : 0;
        int cnt = min(64, e1 - base);
        for (int j = 0; j < cnt; ++j) {
            int sj = __shfl(sreg, j);
            acc += bflo2f((unsigned)h2u[(size_t)sj * OUT_F + lane]);
        }
    }

    float di = 1.0f / fmaxf((float)deg[node], 1.0f);
    float v = acc * di;

    float m = v;
#pragma unroll
    for (int off = 32; off >= 1; off >>= 1)
        m = fmaxf(m, __shfl_xor(m, off));
    float e = expf(v - m);
    float s = e;
#pragma unroll
    for (int off = 32; off >= 1; off >>= 1)
        s += __shfl_xor(s, off);
    out[(size_t)node * OUT_F + lane] = v - m - logf(s);
}

// ---------------------------------------------------------------------------
extern "C" void kernel_launch(void* const* d_in, const int* in_sizes, int n_in,
                              void* d_out, int out_size, void* d_ws, size_t ws_size,
                              hipStream_t stream)
{
    const float* x  = (const float*)d_in[0];
    const int*   ei = (const int*)d_in[1];
    const float* w1 = (const float*)d_in[2];
    const float* b1 = (const float*)d_in[3];
    const float* c1 = (const float*)d_in[4];
    const float* w2 = (const float*)d_in[5];
    const float* b2 = (const float*)d_in[6];
    const float* c2 = (const float*)d_in[7];
    float* out = (float*)d_out;

    const int* src = ei;            // edge_index[0]
    const int* tgt = ei + N_EDGES;  // edge_index[1]

    char* ws = (char*)d_ws;
    size_t off = 0;
    auto carve = [&](size_t bytes) -> void* {
        void* p = ws + off;
        off = (off + bytes + 255) & ~(size_t)255;
        return p;
    };
    short* Wb1       = (short*)carve((size_t)K_TOT * HID_F * 2);
    short* Wb2       = (short*)carve((size_t)K_TOT * OUT_F * 2);
    int*   deg       = (int*)carve((size_t)N_NODES * 4);
    int*   row_start = (int*)carve(((size_t)N_NODES + 1) * 4);
    int*   bsum      = (int*)carve((size_t)NB_SCAN * 4);
    int*   bucket_cnt= (int*)carve((size_t)NBUCK * 4);
    int*   boff      = (int*)carve(((size_t)NBUCK + 1) * 4);
    int*   bcur      = (int*)carve((size_t)NBUCK * 4);
    int*   skey      = (int*)carve((size_t)N_EDGES * 4);
    int*   sval      = (int*)carve((size_t)N_EDGES * 4);
    int*   csr_src   = (int*)carve((size_t)N_EDGES * 4);
    short* h1        = (short*)carve((size_t)N_NODES * HID_F * 2);   // bf16
    float* a1        = (float*)carve((size_t)N_NODES * IN_F * 4);    // fp32
    short* h2        = (short*)carve((size_t)N_NODES * OUT_F * 2);   // bf16

    const int grid_mm = (N_NODES + 63) / 64;   // 1563

    // --- CSR build via bucket sort ------------------------------------------
    hipMemsetAsync(bucket_cnt, 0, (size_t)NBUCK * 4, stream);
    bucket_hist<<<NBLK_SORT, 256, 0, stream>>>(tgt, bucket_cnt);
    bucket_scan<<<1, 256, 0, stream>>>(bucket_cnt, boff, bcur);
    bucket_scatter<<<NBLK_SORT, 256, 0, stream>>>(src, tgt, bcur, skey, sval);
    bucket_deg<<<NBUCK, 256, 0, stream>>>(boff, skey, deg);
    scan_bsum<<<NB_SCAN, 256, 0, stream>>>(deg, bsum, N_NODES);
    scan_top<<<1, 512, 0, stream>>>(bsum, NB_SCAN);
    scan_final<<<NB_SCAN, 256, 0, stream>>>(deg, bsum, row_start, N_NODES);
    csr_fine<<<NBUCK, 256, 0, stream>>>(boff, skey, sval, row_start, csr_src);

    // --- weights + layer 1 ---------------------------------------------------
    fold_weights_bf16<<<(K_TOT * HID_F + K_TOT * OUT_F + 255) / 256, 256, 0, stream>>>(
        w1, c1, w2, c2, Wb1, Wb2);
    kan1_mfma<<<grid_mm, 256, 0, stream>>>(x, Wb1, b1, h1);

    // --- aggregate 1 (gather, no atomics) ------------------------------------
    gather128<<<(N_NODES + 3) / 4, 256, 0, stream>>>((const unsigned*)h1, row_start, csr_src, a1);

    // --- layer 2 -------------------------------------------------------------
    kan2_mfma<<<grid_mm, 256, 0, stream>>>(a1, deg, Wb2, b2, h2);

    // --- aggregate 2 + log_softmax (fused) -----------------------------------
    gather64_lsm<<<(N_NODES + 3) / 4, 256, 0, stream>>>(
        (const unsigned short*)h2, row_start, csr_src, deg, out);
}

// Round 6
// 376.214 us; speedup vs baseline: 12.5239x; 1.1976x over previous
//
#include <hip/hip_runtime.h>
#include <hip/hip_bf16.h>
#include <math.h>

#define N_NODES 100000
#define N_EDGES 1600000
#define IN_F 128
#define HID_F 128
#define OUT_F 64
#define K_TOT 384                          // 3 basis planes x 128
#define NB_SCAN ((N_NODES + 255) / 256)    // 391
#define XLDS_STRIDE 132                    // 128 + 4 pad -> conflict-free b128 reads

// bucket sort parameters
#define BK_BITS 9
#define BK_SIZE 512                        // nodes per bucket
#define NBUCK ((N_NODES + BK_SIZE - 1) / BK_SIZE)   // 196
#define EPB 4096                           // edges per sort block
#define NBLK_SORT ((N_EDGES + EPB - 1) / EPB)       // 391

typedef __attribute__((ext_vector_type(8))) short s8v;   // 8 bf16 (MFMA A/B frag)
typedef __attribute__((ext_vector_type(4))) float f4v;   // MFMA C/D frag

__device__ __forceinline__ short f2bf(float f) {
    __hip_bfloat16 h = __float2bfloat16(f);
    return __builtin_bit_cast(short, h);
}
__device__ __forceinline__ float bfhi2f(unsigned u) {
    return __builtin_bit_cast(float, u & 0xffff0000u);
}
__device__ __forceinline__ float bflo2f(unsigned u) {
    return __builtin_bit_cast(float, u << 16);
}

// ---------------------------------------------------------------------------
// Fold KAN weights into bf16 MFMA-B chunk layout: Wb[c][n][8], c = k>>3.
// ---------------------------------------------------------------------------
__global__ __launch_bounds__(256) void fold_weights_bf16(
    const float* __restrict__ w1, const float* __restrict__ c1,
    const float* __restrict__ w2, const float* __restrict__ c2,
    short* __restrict__ Wb1, short* __restrict__ Wb2)
{
    int idx = blockIdx.x * 256 + threadIdx.x;
    if (idx < K_TOT * HID_F) {
        int k = idx >> 7, n = idx & 127;
        int p = k >> 7, f = k & 127;
        int si = f * HID_F + n;
        float v = (p == 0) ? (w1[si] + 0.1f * c1[si * 3])
                           : 0.1f * c1[si * 3 + p];
        Wb1[(((k >> 3) * HID_F) + n) * 8 + (k & 7)] = f2bf(v);
    } else {
        idx -= K_TOT * HID_F;
        if (idx < K_TOT * OUT_F) {
            int k = idx >> 6, n = idx & 63;
            int p = k >> 7, f = k & 127;
            int si = f * OUT_F + n;
            float v = (p == 0) ? (w2[si] + 0.1f * c2[si * 3])
                               : 0.1f * c2[si * 3 + p];
            Wb2[(((k >> 3) * OUT_F) + n) * 8 + (k & 7)] = f2bf(v);
        }
    }
}

// ---------------------------------------------------------------------------
// Bucket sort pass A: coarse histogram (LDS) -> global bucket counts.
// ---------------------------------------------------------------------------
__global__ __launch_bounds__(256) void bucket_hist(
    const int* __restrict__ tgt, int* __restrict__ bucket_cnt)
{
    __shared__ int h[NBUCK];
    int tid = threadIdx.x;
    for (int i = tid; i < NBUCK; i += 256) h[i] = 0;
    __syncthreads();
    int e0 = blockIdx.x * EPB;
    int n = min(EPB, N_EDGES - e0);
    for (int i = tid; i < n; i += 256)
        atomicAdd(&h[tgt[e0 + i] >> BK_BITS], 1);
    __syncthreads();
    for (int i = tid; i < NBUCK; i += 256)
        if (h[i]) atomicAdd(&bucket_cnt[i], h[i]);
}

// Pass B: single-block exclusive scan of bucket counts -> offsets + cursors.
__global__ __launch_bounds__(256) void bucket_scan(
    const int* __restrict__ cnt, int* __restrict__ boff, int* __restrict__ bcur)
{
    __shared__ int s[256];
    int tid = threadIdx.x;
    int v = (tid < NBUCK) ? cnt[tid] : 0;
    s[tid] = v;
    __syncthreads();
    for (int o = 1; o < 256; o <<= 1) {
        int t = (tid >= o) ? s[tid - o] : 0;
        __syncthreads();
        s[tid] += t;
        __syncthreads();
    }
    int excl = s[tid] - v;
    if (tid < NBUCK) { boff[tid] = excl; bcur[tid] = excl; }
    if (tid == NBUCK - 1) boff[NBUCK] = excl + v;
}

// Pass C: scatter edges into bucket-sorted (tgt,src) arrays.
__global__ __launch_bounds__(256) void bucket_scatter(
    const int* __restrict__ src, const int* __restrict__ tgt,
    int* __restrict__ bcur, int* __restrict__ skey, int* __restrict__ sval)
{
    __shared__ int h[NBUCK];
    __shared__ int base[NBUCK];
    int tid = threadIdx.x;
    for (int i = tid; i < NBUCK; i += 256) h[i] = 0;
    __syncthreads();
    int e0 = blockIdx.x * EPB;
    int n = min(EPB, N_EDGES - e0);
    for (int i = tid; i < n; i += 256)
        atomicAdd(&h[tgt[e0 + i] >> BK_BITS], 1);
    __syncthreads();
    for (int i = tid; i < NBUCK; i += 256) {
        int c = h[i];
        base[i] = c ? atomicAdd(&bcur[i], c) : 0;
        h[i] = 0;
    }
    __syncthreads();
    for (int i = tid; i < n; i += 256) {
        int t = tgt[e0 + i];
        int b = t >> BK_BITS;
        int pos = base[b] + atomicAdd(&h[b], 1);
        skey[pos] = t;
        sval[pos] = src[e0 + i];
    }
}

// Pass D: per-bucket degree via LDS histogram.
__global__ __launch_bounds__(256) void bucket_deg(
    const int* __restrict__ boff, const int* __restrict__ skey,
    int* __restrict__ deg)
{
    __shared__ int d[BK_SIZE];
    int tid = threadIdx.x;
    int b = blockIdx.x;
    for (int i = tid; i < BK_SIZE; i += 256) d[i] = 0;
    __syncthreads();
    int e0 = boff[b], e1 = boff[b + 1];
    int nbase = b << BK_BITS;
    for (int i = e0 + tid; i < e1; i += 256)
        atomicAdd(&d[skey[i] - nbase], 1);
    __syncthreads();
    for (int i = tid; i < BK_SIZE; i += 256) {
        int nd = nbase + i;
        if (nd < N_NODES) deg[nd] = d[i];
    }
}

// ---------------------------------------------------------------------------
// row_start scan over deg (3-kernel).
// ---------------------------------------------------------------------------
__global__ __launch_bounds__(256) void scan_bsum(
    const int* __restrict__ deg, int* __restrict__ bsum, int n)
{
    __shared__ int s[256];
    int tid = threadIdx.x;
    int i = blockIdx.x * 256 + tid;
    s[tid] = (i < n) ? deg[i] : 0;
    __syncthreads();
    for (int o = 128; o > 0; o >>= 1) {
        if (tid < o) s[tid] += s[tid + o];
        __syncthreads();
    }
    if (tid == 0) bsum[blockIdx.x] = s[0];
}

__global__ __launch_bounds__(512) void scan_top(int* __restrict__ bsum, int nb)
{
    __shared__ int s[512];
    int tid = threadIdx.x;
    int v = (tid < nb) ? bsum[tid] : 0;
    s[tid] = v;
    __syncthreads();
    for (int o = 1; o < 512; o <<= 1) {
        int t = (tid >= o) ? s[tid - o] : 0;
        __syncthreads();
        s[tid] += t;
        __syncthreads();
    }
    if (tid < nb) bsum[tid] = s[tid] - v;   // exclusive
}

__global__ __launch_bounds__(256) void scan_final(
    const int* __restrict__ deg, const int* __restrict__ bsum,
    int* __restrict__ row_start, int n)
{
    __shared__ int s[256];
    int tid = threadIdx.x;
    int i = blockIdx.x * 256 + tid;
    int v = (i < n) ? deg[i] : 0;
    s[tid] = v;
    __syncthreads();
    for (int o = 1; o < 256; o <<= 1) {
        int t = (tid >= o) ? s[tid - o] : 0;
        __syncthreads();
        s[tid] += t;
        __syncthreads();
    }
    int excl = s[tid] - v + bsum[blockIdx.x];
    if (i < n) row_start[i] = excl;
    if (i == n - 1) row_start[n] = excl + v;
}

// Pass E: fine CSR fill (LDS cursors, contiguous write window per block).
__global__ __launch_bounds__(256) void csr_fine(
    const int* __restrict__ boff, const int* __restrict__ skey,
    const int* __restrict__ sval, const int* __restrict__ row_start,
    int* __restrict__ csr_src)
{
    __shared__ int cur[BK_SIZE];
    int tid = threadIdx.x;
    int b = blockIdx.x;
    int nbase = b << BK_BITS;
    for (int i = tid; i < BK_SIZE; i += 256) {
        int nd = nbase + i;
        cur[i] = (nd < N_NODES) ? row_start[nd] : 0;
    }
    __syncthreads();
    int e0 = boff[b], e1 = boff[b + 1];
    for (int i = e0 + tid; i < e1; i += 256) {
        int pos = atomicAdd(&cur[skey[i] - nbase], 1);
        csr_src[pos] = sval[i];
    }
}

// ---------------------------------------------------------------------------
// KAN1 via MFMA bf16 (block = 64 nodes x 128 out, 4 waves 2x2).
// ---------------------------------------------------------------------------
__global__ __launch_bounds__(256) void kan1_mfma(
    const float* __restrict__ x, const short* __restrict__ Wb,
    const float* __restrict__ bias, short* __restrict__ h1)
{
    __shared__ float sx[64 * XLDS_STRIDE];
    const int tid  = threadIdx.x;
    const int lane = tid & 63;
    const int wave = tid >> 6;
    const int node0 = blockIdx.x * 64;
    const int q = lane >> 4, r = lane & 15;

#pragma unroll
    for (int it = 0; it < 8; ++it) {
        int idx = tid + 256 * it;
        int m = idx >> 5, c4 = (idx & 31) * 4;
        int gm = min(node0 + m, N_NODES - 1);
        float4 v = *(const float4*)(x + (size_t)gm * IN_F + c4);
        *(float4*)(sx + m * XLDS_STRIDE + c4) = v;
    }
    __syncthreads();

    const int wm = (wave & 1) * 32;
    const int wn = (wave >> 1) * 64;

    f4v acc[2][4];
#pragma unroll
    for (int i = 0; i < 2; ++i)
#pragma unroll
        for (int j = 0; j < 4; ++j)
            acc[i][j] = (f4v){0.f, 0.f, 0.f, 0.f};

    float bj[4];
#pragma unroll
    for (int j = 0; j < 4; ++j) bj[j] = bias[wn + j * 16 + r];

#pragma unroll
    for (int kb = 0; kb < 12; ++kb) {
        const int p  = kb >> 2;
        const int f0 = (kb & 3) * 32 + q * 8;

        s8v afrag[2];
#pragma unroll
        for (int i = 0; i < 2; ++i) {
            const float* xs = sx + (wm + i * 16 + r) * XLDS_STRIDE + f0;
            float4 v0 = *(const float4*)xs;
            float4 v1 = *(const float4*)(xs + 4);
            float v[8] = {v0.x, v0.y, v0.z, v0.w, v1.x, v1.y, v1.z, v1.w};
            s8v a;
#pragma unroll
            for (int t = 0; t < 8; ++t) {
                float e = v[t];
                if (p >= 1) e *= v[t];
                if (p == 2) e *= v[t];
                a[t] = f2bf(e);
            }
            afrag[i] = a;
        }
#pragma unroll
        for (int j = 0; j < 4; ++j) {
            const s8v b = *(const s8v*)(Wb + (((kb * 4 + q) * HID_F) + wn + j * 16 + r) * 8);
            acc[0][j] = __builtin_amdgcn_mfma_f32_16x16x32_bf16(afrag[0], b, acc[0][j], 0, 0, 0);
            acc[1][j] = __builtin_amdgcn_mfma_f32_16x16x32_bf16(afrag[1], b, acc[1][j], 0, 0, 0);
        }
    }

#pragma unroll
    for (int i = 0; i < 2; ++i)
#pragma unroll
        for (int j = 0; j < 4; ++j)
#pragma unroll
            for (int e = 0; e < 4; ++e) {
                int grow = node0 + wm + i * 16 + q * 4 + e;
                if (grow < N_NODES) {
                    int gcol = wn + j * 16 + r;
                    h1[(size_t)grow * HID_F + gcol] =
                        f2bf(fmaxf(acc[i][j][e] + bj[j], 0.f));
                }
            }
}

// ---------------------------------------------------------------------------
// KAN2 via MFMA bf16 (block = 64 nodes x 64 out); 1/deg fused at staging.
// ---------------------------------------------------------------------------
__global__ __launch_bounds__(256) void kan2_mfma(
    const float* __restrict__ a1, const int* __restrict__ deg,
    const short* __restrict__ Wb, const float* __restrict__ bias,
    short* __restrict__ h2)
{
    __shared__ float sx[64 * XLDS_STRIDE];
    const int tid  = threadIdx.x;
    const int lane = tid & 63;
    const int wave = tid >> 6;
    const int node0 = blockIdx.x * 64;
    const int q = lane >> 4, r = lane & 15;

#pragma unroll
    for (int it = 0; it < 8; ++it) {
        int idx = tid + 256 * it;
        int m = idx >> 5, c4 = (idx & 31) * 4;
        int gm = min(node0 + m, N_NODES - 1);
        float di = 1.0f / fmaxf((float)deg[gm], 1.0f);
        float4 v = *(const float4*)(a1 + (size_t)gm * IN_F + c4);
        v.x *= di; v.y *= di; v.z *= di; v.w *= di;
        *(float4*)(sx + m * XLDS_STRIDE + c4) = v;
    }
    __syncthreads();

    const int wm = (wave & 1) * 32;
    const int wn = (wave >> 1) * 32;

    f4v acc[2][2];
#pragma unroll
    for (int i = 0; i < 2; ++i)
#pragma unroll
        for (int j = 0; j < 2; ++j)
            acc[i][j] = (f4v){0.f, 0.f, 0.f, 0.f};

    float bj[2];
#pragma unroll
    for (int j = 0; j < 2; ++j) bj[j] = bias[wn + j * 16 + r];

#pragma unroll
    for (int kb = 0; kb < 12; ++kb) {
        const int p  = kb >> 2;
        const int f0 = (kb & 3) * 32 + q * 8;

        s8v afrag[2];
#pragma unroll
        for (int i = 0; i < 2; ++i) {
            const float* xs = sx + (wm + i * 16 + r) * XLDS_STRIDE + f0;
            float4 v0 = *(const float4*)xs;
            float4 v1 = *(const float4*)(xs + 4);
            float v[8] = {v0.x, v0.y, v0.z, v0.w, v1.x, v1.y, v1.z, v1.w};
            s8v a;
#pragma unroll
            for (int t = 0; t < 8; ++t) {
                float e = v[t];
                if (p >= 1) e *= v[t];
                if (p == 2) e *= v[t];
                a[t] = f2bf(e);
            }
            afrag[i] = a;
        }
#pragma unroll
        for (int j = 0; j < 2; ++j) {
            const s8v b = *(const s8v*)(Wb + (((kb * 4 + q) * OUT_F) + wn + j * 16 + r) * 8);
            acc[0][j] = __builtin_amdgcn_mfma_f32_16x16x32_bf16(afrag[0], b, acc[0][j], 0, 0, 0);
            acc[1][j] = __builtin_amdgcn_mfma_f32_16x16x32_bf16(afrag[1], b, acc[1][j], 0, 0, 0);
        }
    }

#pragma unroll
    for (int i = 0; i < 2; ++i)
#pragma unroll
        for (int j = 0; j < 2; ++j)
#pragma unroll
            for (int e = 0; e < 4; ++e) {
                int grow = node0 + wm + i * 16 + q * 4 + e;
                if (grow < N_NODES) {
                    int gcol = wn + j * 16 + r;
                    h2[(size_t)grow * OUT_F + gcol] = f2bf(acc[i][j][e] + bj[j]);
                }
            }
}

// ---------------------------------------------------------------------------
// Gather-aggregate over 128 bf16 feats -> fp32 out.  8 independent
// accumulator chains -> 8 outstanding loads per wave (latency-bound fix).
// ---------------------------------------------------------------------------
__global__ __launch_bounds__(256) void gather128(
    const unsigned* __restrict__ h1u, const int* __restrict__ row_start,
    const int* __restrict__ csr_src, float* __restrict__ out)
{
    const int lane = threadIdx.x & 63;
    const int wave = threadIdx.x >> 6;
    const int node = blockIdx.x * 4 + wave;
    if (node >= N_NODES) return;

    int e0 = row_start[node], e1 = row_start[node + 1];
    float ax[8], ay[8];
#pragma unroll
    for (int t = 0; t < 8; ++t) { ax[t] = 0.f; ay[t] = 0.f; }

    for (int base = e0; base < e1; base += 64) {
        int idx = base + lane;
        int sreg = (idx < e1) ? csr_src[idx] : 0;
        int cnt = min(64, e1 - base);
        int j = 0;
        for (; j + 8 <= cnt; j += 8) {
            unsigned u[8];
#pragma unroll
            for (int t = 0; t < 8; ++t) {
                int sj = __shfl(sreg, j + t);
                u[t] = h1u[(size_t)sj * 64 + lane];
            }
#pragma unroll
            for (int t = 0; t < 8; ++t) {
                ax[t] += bflo2f(u[t]);
                ay[t] += bfhi2f(u[t]);
            }
        }
        for (; j < cnt; ++j) {
            int sj = __shfl(sreg, j);
            unsigned u = h1u[(size_t)sj * 64 + lane];
            ax[0] += bflo2f(u);
            ay[0] += bfhi2f(u);
        }
    }
    float sx = ((ax[0] + ax[1]) + (ax[2] + ax[3])) + ((ax[4] + ax[5]) + (ax[6] + ax[7]));
    float sy = ((ay[0] + ay[1]) + (ay[2] + ay[3])) + ((ay[4] + ay[5]) + (ay[6] + ay[7]));
    float2 rv; rv.x = sx; rv.y = sy;
    ((float2*)out)[(size_t)node * 64 + lane] = rv;
}

// ---------------------------------------------------------------------------
// Gather-aggregate over 64 bf16 feats fused with 1/deg + log_softmax.
// 8 accumulator chains for MLP.
// ---------------------------------------------------------------------------
__global__ __launch_bounds__(256) void gather64_lsm(
    const unsigned short* __restrict__ h2u, const int* __restrict__ row_start,
    const int* __restrict__ csr_src, const int* __restrict__ deg,
    float* __restrict__ out)
{
    const int lane = threadIdx.x & 63;
    const int wave = threadIdx.x >> 6;
    const int node = blockIdx.x * 4 + wave;
    if (node >= N_NODES) return;

    int e0 = row_start[node], e1 = row_start[node + 1];
    float a[8];
#pragma unroll
    for (int t = 0; t < 8; ++t) a[t] = 0.f;

    for (int base = e0; base < e1; base += 64) {
        int idx = base + lane;
        int sreg = (idx < e1) ? csr_src[idx] : 0;
        int cnt = min(64, e1 - base);
        int j = 0;
        for (; j + 8 <= cnt; j += 8) {
            unsigned short u[8];
#pragma unroll
            for (int t = 0; t < 8; ++t) {
                int sj = __shfl(sreg, j + t);
                u[t] = h2u[(size_t)sj * OUT_F + lane];
            }
#pragma unroll
            for (int t = 0; t < 8; ++t)
                a[t] += bflo2f((unsigned)u[t]);
        }
        for (; j < cnt; ++j) {
            int sj = __shfl(sreg, j);
            a[0] += bflo2f((unsigned)h2u[(size_t)sj * OUT_F + lane]);
        }
    }
    float acc = ((a[0] + a[1]) + (a[2] + a[3])) + ((a[4] + a[5]) + (a[6] + a[7]));

    float di = 1.0f / fmaxf((float)deg[node], 1.0f);
    float v = acc * di;

    float m = v;
#pragma unroll
    for (int off = 32; off >= 1; off >>= 1)
        m = fmaxf(m, __shfl_xor(m, off));
    float e = expf(v - m);
    float s = e;
#pragma unroll
    for (int off = 32; off >= 1; off >>= 1)
        s += __shfl_xor(s, off);
    out[(size_t)node * OUT_F + lane] = v - m - logf(s);
}

// ---------------------------------------------------------------------------
extern "C" void kernel_launch(void* const* d_in, const int* in_sizes, int n_in,
                              void* d_out, int out_size, void* d_ws, size_t ws_size,
                              hipStream_t stream)
{
    const float* x  = (const float*)d_in[0];
    const int*   ei = (const int*)d_in[1];
    const float* w1 = (const float*)d_in[2];
    const float* b1 = (const float*)d_in[3];
    const float* c1 = (const float*)d_in[4];
    const float* w2 = (const float*)d_in[5];
    const float* b2 = (const float*)d_in[6];
    const float* c2 = (const float*)d_in[7];
    float* out = (float*)d_out;

    const int* src = ei;            // edge_index[0]
    const int* tgt = ei + N_EDGES;  // edge_index[1]

    char* ws = (char*)d_ws;
    size_t off = 0;
    auto carve = [&](size_t bytes) -> void* {
        void* p = ws + off;
        off = (off + bytes + 255) & ~(size_t)255;
        return p;
    };
    short* Wb1       = (short*)carve((size_t)K_TOT * HID_F * 2);
    short* Wb2       = (short*)carve((size_t)K_TOT * OUT_F * 2);
    int*   deg       = (int*)carve((size_t)N_NODES * 4);
    int*   row_start = (int*)carve(((size_t)N_NODES + 1) * 4);
    int*   bsum      = (int*)carve((size_t)NB_SCAN * 4);
    int*   bucket_cnt= (int*)carve((size_t)NBUCK * 4);
    int*   boff      = (int*)carve(((size_t)NBUCK + 1) * 4);
    int*   bcur      = (int*)carve((size_t)NBUCK * 4);
    int*   skey      = (int*)carve((size_t)N_EDGES * 4);
    int*   sval      = (int*)carve((size_t)N_EDGES * 4);
    int*   csr_src   = (int*)carve((size_t)N_EDGES * 4);
    short* h1        = (short*)carve((size_t)N_NODES * HID_F * 2);   // bf16
    float* a1        = (float*)carve((size_t)N_NODES * IN_F * 4);    // fp32
    short* h2        = (short*)carve((size_t)N_NODES * OUT_F * 2);   // bf16

    const int grid_mm = (N_NODES + 63) / 64;   // 1563

    // --- CSR build via bucket sort ------------------------------------------
    hipMemsetAsync(bucket_cnt, 0, (size_t)NBUCK * 4, stream);
    bucket_hist<<<NBLK_SORT, 256, 0, stream>>>(tgt, bucket_cnt);
    bucket_scan<<<1, 256, 0, stream>>>(bucket_cnt, boff, bcur);
    bucket_scatter<<<NBLK_SORT, 256, 0, stream>>>(src, tgt, bcur, skey, sval);
    bucket_deg<<<NBUCK, 256, 0, stream>>>(boff, skey, deg);
    scan_bsum<<<NB_SCAN, 256, 0, stream>>>(deg, bsum, N_NODES);
    scan_top<<<1, 512, 0, stream>>>(bsum, NB_SCAN);
    scan_final<<<NB_SCAN, 256, 0, stream>>>(deg, bsum, row_start, N_NODES);
    csr_fine<<<NBUCK, 256, 0, stream>>>(boff, skey, sval, row_start, csr_src);

    // --- weights + layer 1 ---------------------------------------------------
    fold_weights_bf16<<<(K_TOT * HID_F + K_TOT * OUT_F + 255) / 256, 256, 0, stream>>>(
        w1, c1, w2, c2, Wb1, Wb2);
    kan1_mfma<<<grid_mm, 256, 0, stream>>>(x, Wb1, b1, h1);

    // --- aggregate 1 (gather, no atomics) ------------------------------------
    gather128<<<(N_NODES + 3) / 4, 256, 0, stream>>>((const unsigned*)h1, row_start, csr_src, a1);

    // --- layer 2 -------------------------------------------------------------
    kan2_mfma<<<grid_mm, 256, 0, stream>>>(a1, deg, Wb2, b2, h2);

    // --- aggregate 2 + log_softmax (fused) -----------------------------------
    gather64_lsm<<<(N_NODES + 3) / 4, 256, 0, stream>>>(
        (const unsigned short*)h2, row_start, csr_src, deg, out);
}